// Round 2
// baseline (1856.113 us; speedup 1.0000x reference)
//
#include <hip/hip_runtime.h>
#include <hip/hip_fp16.h>
#include <math.h>

// Problem constants: B=4, C=64, H=W=256, D=16, C4=256, P=8.  HW=65536.

typedef _Float16 half2_t __attribute__((ext_vector_type(2)));

__device__ __forceinline__ unsigned short f2h(float f) {
  return __builtin_bit_cast(unsigned short, (_Float16)f);
}
__device__ __forceinline__ float h2f(unsigned short u) {
  return (float)__builtin_bit_cast(_Float16, u);
}
__device__ __forceinline__ float gelu_f(float x) {
  return 0.5f * x * (1.0f + erff(x * 0.70710678118654752440f));
}

// ---------------------------------------------------------------------------
// κ_c[a][b] = (1/64) Σ_{u,v} W̃[u][v] cos(2π(ua+vb)/8);  W̃[u][v<=4]=fw[u][v],
// W̃[u][v>=5]=fw[(8-u)&7][8-v].  irfft2(rfft2(x)·fw) == circular conv with κ
// (cos-only kernel == Re of complex kernel == pocketfft c2r behavior, which
// drops Im of DC/Nyquist bins).
// ---------------------------------------------------------------------------
__global__ void build_kappa_kernel(const float* __restrict__ fw1,
                                   const float* __restrict__ fw2,
                                   float* __restrict__ kap1,
                                   float* __restrict__ kap2) {
  int which = blockIdx.x >> 6;
  int c = blockIdx.x & 63;
  const float* fw = which ? fw2 : fw1;
  float* kap = which ? kap2 : kap1;
  int t = threadIdx.x;            // 64 threads: t = a*8+b
  int a = t >> 3, bb = t & 7;
  __shared__ float Wt[64];
  __shared__ float ct[8];
  if (t == 0) {
    const float r2 = 0.70710678118654752440f;
    ct[0] = 1.f; ct[1] = r2; ct[2] = 0.f; ct[3] = -r2;
    ct[4] = -1.f; ct[5] = -r2; ct[6] = 0.f; ct[7] = r2;
  }
  {
    int u = a, v = bb;
    float wv = (v <= 4) ? fw[c * 40 + u * 5 + v]
                        : fw[c * 40 + ((8 - u) & 7) * 5 + (8 - v)];
    Wt[t] = wv;
  }
  __syncthreads();
  float acc = 0.f;
  for (int u = 0; u < 8; ++u)
    for (int v = 0; v < 8; ++v)
      acc += Wt[u * 8 + v] * ct[(u * a + v * bb) & 7];
  kap[c * 64 + t] = acc * 0.015625f;
}

// ---------------------------------------------------------------------------
// LayerNorm over channel dim (64) per pixel.  x -> xn (in d_out), f32.
// ---------------------------------------------------------------------------
__global__ void __launch_bounds__(256) ln_kernel(const float* __restrict__ x,
                                                 const float* __restrict__ lnw,
                                                 const float* __restrict__ lnb,
                                                 float* __restrict__ xn) {
  int p = blockIdx.x * 256 + threadIdx.x;   // 0..262143
  int b = p >> 16, hw = p & 65535;
  const float* xp = x + ((size_t)b << 22) + hw;
  float v[64];
  float s = 0.f;
#pragma unroll
  for (int c = 0; c < 64; ++c) { v[c] = xp[(size_t)c << 16]; s += v[c]; }
  float mu = s * (1.f / 64.f);
  float s2 = 0.f;
#pragma unroll
  for (int c = 0; c < 64; ++c) { float d = v[c] - mu; s2 += d * d; }
  float rstd = rsqrtf(s2 * (1.f / 64.f) + 1e-6f);
  float* op = xn + ((size_t)b << 22) + hw;
#pragma unroll
  for (int c = 0; c < 64; ++c)
    op[(size_t)c << 16] = (v[c] - mu) * rstd * lnw[c] + lnb[c];
}

// ---------------------------------------------------------------------------
// 3x3 SAME conv on xn channels 0..15 -> y1 (B,16,256,256) f16.
// ---------------------------------------------------------------------------
__global__ void __launch_bounds__(256) pconv_kernel(
    const float* __restrict__ xn, const float* __restrict__ pw,
    const float* __restrict__ pb, unsigned short* __restrict__ y1) {
  __shared__ float tile[16][324];   // 16 ci x 18x18
  __shared__ float wsh[2304];
  int blk = blockIdx.x;             // b*256 + ty*16 + tx
  int b = blk >> 8, ty = (blk >> 4) & 15, tx = blk & 15;
  int h0 = ty << 4, w0 = tx << 4;
  for (int i = threadIdx.x; i < 16 * 324; i += 256) {
    int ci = i / 324, pp = i - ci * 324;
    int r = pp / 18, col = pp - r * 18;
    int h = h0 + r - 1, w = w0 + col - 1;
    float v = 0.f;
    if ((unsigned)h < 256u && (unsigned)w < 256u)
      v = xn[(((size_t)(b * 64 + ci)) << 16) + (h << 8) + w];
    tile[ci][pp] = v;
  }
  for (int i = threadIdx.x; i < 2304; i += 256) wsh[i] = pw[i];
  __syncthreads();
  int py = threadIdx.x >> 4, px = threadIdx.x & 15;
#pragma unroll 2
  for (int co = 0; co < 16; ++co) {
    float acc = pb[co];
    for (int ci = 0; ci < 16; ++ci) {
      const float* tp = &tile[ci][py * 18 + px];
      const float* wp = &wsh[(co * 16 + ci) * 9];
#pragma unroll
      for (int ky = 0; ky < 3; ++ky)
#pragma unroll
        for (int kx = 0; kx < 3; ++kx)
          acc += tp[ky * 18 + kx] * wp[ky * 3 + kx];
    }
    y1[(((size_t)(b * 16 + co)) << 16) + ((h0 + py) << 8) + (w0 + px)] =
        f2h(acc);
  }
}

// ---------------------------------------------------------------------------
// 1x1 expand (64 -> 256) + bias + GELU, f16 out.  BR2: ci<16 from y1.
// Per-batch: grid 2048 = 1024 hw-tiles(64px) * 2 ce-halves(128).
// ---------------------------------------------------------------------------
template <int BR2>
__global__ void __launch_bounds__(256) expand_kernel(
    const float* __restrict__ xn, const unsigned short* __restrict__ y1,
    const float* __restrict__ W, const float* __restrict__ bias,
    unsigned short* __restrict__ e, int b) {
  int blk = blockIdx.x;             // 0..2047
  int hw0 = (blk >> 1) << 6;
  int ce0 = (blk & 1) << 7;
  __shared__ float xin[64][64];     // [ci][px]
  __shared__ float Wt[64][128];     // [ci][ce_local]
  for (int i = threadIdx.x; i < 4096; i += 256) {
    int ci = i >> 6, px = i & 63;
    float v;
    if (BR2 && ci < 16)
      v = h2f(y1[(((size_t)(b * 16 + ci)) << 16) + hw0 + px]);
    else
      v = xn[(((size_t)(b * 64 + ci)) << 16) + hw0 + px];
    xin[ci][px] = v;
  }
  for (int i = threadIdx.x; i < 8192; i += 256) {
    int ce = i & 127, k = i >> 7;
    Wt[k][ce] = W[((ce0 + ce) << 6) + k];
  }
  __syncthreads();
  int l = threadIdx.x & 63, wv = threadIdx.x >> 6;
  int px0 = (l & 15) << 2;
  int cl0 = wv * 32 + ((l >> 4) << 3);   // local ce base (mult of 8)
  float acc[8][4];
#pragma unroll
  for (int i = 0; i < 8; ++i)
#pragma unroll
    for (int j = 0; j < 4; ++j) acc[i][j] = 0.f;
#pragma unroll 4
  for (int k = 0; k < 64; ++k) {
    float xr[4], wr[8];
    *(float4*)&xr[0] = *(const float4*)&xin[k][px0];
    *(float4*)&wr[0] = *(const float4*)&Wt[k][cl0];
    *(float4*)&wr[4] = *(const float4*)&Wt[k][cl0 + 4];
#pragma unroll
    for (int i = 0; i < 8; ++i)
#pragma unroll
      for (int j = 0; j < 4; ++j) acc[i][j] += wr[i] * xr[j];
  }
#pragma unroll
  for (int i = 0; i < 8; ++i) {
    int ce = ce0 + cl0 + i;
    float bz = bias[ce];
    ushort4 pk;
    pk.x = f2h(gelu_f(acc[i][0] + bz));
    pk.y = f2h(gelu_f(acc[i][1] + bz));
    pk.z = f2h(gelu_f(acc[i][2] + bz));
    pk.w = f2h(gelu_f(acc[i][3] + bz));
    *reinterpret_cast<ushort4*>(&e[(((size_t)ce) << 16) + hw0 + px0]) = pk;
  }
}

// ---------------------------------------------------------------------------
// 1x1 contract (256 -> 64) + bias, f16 out.  Per-batch: grid 1024 (64px).
// ---------------------------------------------------------------------------
__global__ void __launch_bounds__(256) contract1_kernel(
    const unsigned short* __restrict__ e, const float* __restrict__ W2,
    const float* __restrict__ b2, unsigned short* __restrict__ u1) {
  int hw0 = blockIdx.x << 6;
  __shared__ float xin[64][64];
  __shared__ float Wt[64][64];
  int l = threadIdx.x & 63, wv = threadIdx.x >> 6;
  int px0 = (l & 15) << 2;
  int co0 = wv * 16 + ((l >> 4) << 2);
  float acc[4][4];
#pragma unroll
  for (int i = 0; i < 4; ++i)
#pragma unroll
    for (int j = 0; j < 4; ++j) acc[i][j] = 0.f;
  for (int kc = 0; kc < 4; ++kc) {
    __syncthreads();
    for (int i = threadIdx.x; i < 4096; i += 256) {
      int kk = i >> 6, px = i & 63;
      xin[kk][px] = h2f(e[(((size_t)(kc * 64 + kk)) << 16) + hw0 + px]);
    }
    for (int i = threadIdx.x; i < 4096; i += 256) {
      int co = i & 63, kk = i >> 6;
      Wt[kk][co] = W2[(co << 8) + kc * 64 + kk];
    }
    __syncthreads();
#pragma unroll 4
    for (int k = 0; k < 64; ++k) {
      float xr[4], wr[4];
      *(float4*)&xr[0] = *(const float4*)&xin[k][px0];
      *(float4*)&wr[0] = *(const float4*)&Wt[k][co0];
#pragma unroll
      for (int i = 0; i < 4; ++i)
#pragma unroll
        for (int j = 0; j < 4; ++j) acc[i][j] += wr[i] * xr[j];
    }
  }
#pragma unroll
  for (int i = 0; i < 4; ++i) {
    int co = co0 + i;
    float bz = b2[co];
    ushort4 o;
    o.x = f2h(acc[i][0] + bz);
    o.y = f2h(acc[i][1] + bz);
    o.z = f2h(acc[i][2] + bz);
    o.w = f2h(acc[i][3] + bz);
    *reinterpret_cast<ushort4*>(&u1[(((size_t)co) << 16) + hw0 + px0]) = o;
  }
}

// ---------------------------------------------------------------------------
// Fused: depthwise 3x3 + b3 + GELU + 1x1 contract (256->64) + b4 -> u2 f16.
// Per-batch: grid 256 = 16x16 pixel tiles (16x16 each).
// ---------------------------------------------------------------------------
__global__ void __launch_bounds__(256) dwcontract2_kernel(
    const unsigned short* __restrict__ e, const float* __restrict__ w3,
    const float* __restrict__ b3, const float* __restrict__ w4,
    const float* __restrict__ b4, unsigned short* __restrict__ u2) {
  int blk = blockIdx.x;             // ty*16 + tx
  int ty = blk >> 4, tx = blk & 15;
  int h0 = ty << 4, w0 = tx << 4;
  __shared__ float tile[16][324];        // 16 ce x 18x18
  __shared__ unsigned short g[16][256];  // gelu(dw) f16, [ce][px]
  __shared__ float Wt[16][64];           // w4 chunk [ce][co]
  int t = threadIdx.x;
  int l = t & 63, wv = t >> 6;
  int py = t >> 4, pxc = t & 15;
  int px0 = l << 2;          // phase-2 pixel base (0..252)
  int co0 = wv << 4;         // phase-2 co base
  float acc[16][4];
#pragma unroll
  for (int i = 0; i < 16; ++i)
#pragma unroll
    for (int j = 0; j < 4; ++j) acc[i][j] = 0.f;

  for (int kc = 0; kc < 16; ++kc) {
    int ce0 = kc << 4;
    __syncthreads();   // previous phase-2 done before overwriting LDS
    for (int i = t; i < 16 * 324; i += 256) {
      int ce = i / 324, pp = i - ce * 324;
      int r = pp / 18, col = pp - r * 18;
      int h = h0 + r - 1, w = w0 + col - 1;
      float v = 0.f;
      if ((unsigned)h < 256u && (unsigned)w < 256u)
        v = h2f(e[(((size_t)(ce0 + ce)) << 16) + (h << 8) + w]);
      tile[ce][pp] = v;
    }
    for (int i = t; i < 1024; i += 256) {
      int co = i & 63, k = i >> 6;
      Wt[k][co] = w4[(co << 8) + ce0 + k];
    }
    __syncthreads();
    // phase 1: depthwise 3x3 + gelu for this ce chunk
#pragma unroll 2
    for (int ce = 0; ce < 16; ++ce) {
      float a9 = b3[ce0 + ce];
      const float* tp = &tile[ce][py * 18 + pxc];
      const float* wp = &w3[(ce0 + ce) * 9];
#pragma unroll
      for (int ky = 0; ky < 3; ++ky)
#pragma unroll
        for (int kx = 0; kx < 3; ++kx)
          a9 += tp[ky * 18 + kx] * wp[ky * 3 + kx];
      g[ce][t] = f2h(gelu_f(a9));
    }
    __syncthreads();
    // phase 2: contract partial GEMM over this chunk
#pragma unroll 4
    for (int k = 0; k < 16; ++k) {
      ushort4 gv = *(const ushort4*)&g[k][px0];
      float xr[4];
      xr[0] = h2f(gv.x); xr[1] = h2f(gv.y);
      xr[2] = h2f(gv.z); xr[3] = h2f(gv.w);
      float wr[16];
      *(float4*)&wr[0]  = *(const float4*)&Wt[k][co0];
      *(float4*)&wr[4]  = *(const float4*)&Wt[k][co0 + 4];
      *(float4*)&wr[8]  = *(const float4*)&Wt[k][co0 + 8];
      *(float4*)&wr[12] = *(const float4*)&Wt[k][co0 + 12];
#pragma unroll
      for (int i = 0; i < 16; ++i)
#pragma unroll
        for (int j = 0; j < 4; ++j) acc[i][j] += wr[i] * xr[j];
    }
  }
#pragma unroll
  for (int i = 0; i < 16; ++i) {
    int co = co0 + i;
    float bz = b4[co];
    ushort4 o;
    o.x = f2h(acc[i][0] + bz);
    o.y = f2h(acc[i][1] + bz);
    o.z = f2h(acc[i][2] + bz);
    o.w = f2h(acc[i][3] + bz);
    *reinterpret_cast<ushort4*>(
        &u2[(((size_t)co) << 16) + ((h0 + (px0 >> 4)) << 8) + w0 +
            (px0 & 15)]) = o;
  }
}

// ---------------------------------------------------------------------------
// out = circconv8x8(u1,κ1) + circconv8x8(u2,κ2).  Wave = one window; lane
// holds (u1,u2) f16-packed; broadcast via readlane + v_dot2_f32_f16 against
// per-lane permuted packed-κ table.  Per-batch: grid 512 = C * 8 parts.
// ---------------------------------------------------------------------------
__global__ void __launch_bounds__(256) fftmix_kernel(
    const unsigned short* __restrict__ u1,
    const unsigned short* __restrict__ u2,
    const float* __restrict__ kap1, const float* __restrict__ kap2,
    float* __restrict__ out, int b) {
  int blk = blockIdx.x;           // 0..511
  int c = blk >> 3, part = blk & 7;
  int l = threadIdx.x & 63, wv = threadIdx.x >> 6;
  int s = l >> 3, tq = l & 7;
  unsigned int kp[64];
#pragma unroll
  for (int j = 0; j < 64; ++j) {
    int idx = (((s - (j >> 3)) & 7) << 3) | ((tq - (j & 7)) & 7);
    kp[j] = (unsigned int)f2h(kap1[(c << 6) + idx]) |
            ((unsigned int)f2h(kap2[(c << 6) + idx]) << 16);
  }
  size_t cb = ((size_t)c) << 16;
  size_t obase = ((size_t)(b * 64 + c)) << 16;
  int win0 = part * 128 + wv * 32;
  for (int it = 0; it < 32; ++it) {
    int win = win0 + it;
    int wh = win >> 5, ww = win & 31;
    size_t pix = (size_t)((wh * 8 + s) << 8) + ww * 8 + tq;
    unsigned int pk = (unsigned int)u1[cb + pix] |
                      ((unsigned int)u2[cb + pix] << 16);
    float acc = 0.f;
#pragma unroll
    for (int j = 0; j < 64; ++j) {
      unsigned int bc = (unsigned int)__builtin_amdgcn_readlane((int)pk, j);
#if __has_builtin(__builtin_amdgcn_fdot2)
      acc = __builtin_amdgcn_fdot2(__builtin_bit_cast(half2_t, bc),
                                   __builtin_bit_cast(half2_t, kp[j]),
                                   acc, false);
#else
      half2_t hv = __builtin_bit_cast(half2_t, bc);
      half2_t hk = __builtin_bit_cast(half2_t, kp[j]);
      acc += (float)hv.x * (float)hk.x + (float)hv.y * (float)hk.y;
#endif
    }
    out[obase + pix] = acc;
  }
}

// ---------------------------------------------------------------------------
// Fallback diagnostic: encode ws_size (MB) into d_out[0] so the absmax
// reveals it if the workspace guard trips again.
// ---------------------------------------------------------------------------
__global__ void diag_kernel(float* __restrict__ out, float code, int n) {
  int i = blockIdx.x * 256 + threadIdx.x;
  for (int p = i; p < n; p += 256 * 4096) out[p] = (p == 0) ? code : 0.f;
}

// ---------------------------------------------------------------------------
extern "C" void kernel_launch(void* const* d_in, const int* in_sizes, int n_in,
                              void* d_out, int out_size, void* d_ws,
                              size_t ws_size, hipStream_t stream) {
  const float* x       = (const float*)d_in[0];
  const float* ln_w    = (const float*)d_in[1];
  const float* ln_b    = (const float*)d_in[2];
  const float* pconv_w = (const float*)d_in[3];
  const float* pconv_b = (const float*)d_in[4];
  const float* w0      = (const float*)d_in[5];
  const float* b0      = (const float*)d_in[6];
  const float* w1      = (const float*)d_in[7];
  const float* b1      = (const float*)d_in[8];
  const float* w2      = (const float*)d_in[9];
  const float* b2      = (const float*)d_in[10];
  const float* w3      = (const float*)d_in[11];
  const float* b3      = (const float*)d_in[12];
  const float* w4      = (const float*)d_in[13];
  const float* b4      = (const float*)d_in[14];
  const float* fftw1   = (const float*)d_in[15];
  const float* fftw2   = (const float*)d_in[16];

  // Workspace layout (~56.03 MB); xn (f32, 64 MB) lives in d_out.
  const size_t OFF_KAP1 = 0;
  const size_t OFF_KAP2 = 16384;
  const size_t OFF_Y1   = 32768;                       // f16 (B,16,HW) = 8 MB
  const size_t OFF_E    = OFF_Y1 + 8388608ull;         // f16 (256,HW)  = 32 MB
  const size_t OFF_U1   = OFF_E + 33554432ull;         // f16 (64,HW)   = 8 MB
  const size_t OFF_U2   = OFF_U1 + 8388608ull;         // f16 (64,HW)   = 8 MB
  const size_t WS_NEED  = OFF_U2 + 8388608ull;         // 58,753,024 B

  float* outF = (float*)d_out;
  if (ws_size < WS_NEED) {
    diag_kernel<<<4096, 256, 0, stream>>>(
        outF, 1000.0f + (float)(ws_size >> 20), 16777216);
    return;
  }

  char* ws = (char*)d_ws;
  float* kap1 = (float*)(ws + OFF_KAP1);
  float* kap2 = (float*)(ws + OFF_KAP2);
  unsigned short* y1h = (unsigned short*)(ws + OFF_Y1);
  unsigned short* ebuf = (unsigned short*)(ws + OFF_E);
  unsigned short* u1h = (unsigned short*)(ws + OFF_U1);
  unsigned short* u2h = (unsigned short*)(ws + OFF_U2);

  build_kappa_kernel<<<128, 64, 0, stream>>>(fftw1, fftw2, kap1, kap2);
  ln_kernel<<<1024, 256, 0, stream>>>(x, ln_w, ln_b, outF);        // xn -> d_out
  pconv_kernel<<<1024, 256, 0, stream>>>(outF, pconv_w, pconv_b, y1h);

  for (int b = 0; b < 4; ++b) {
    expand_kernel<0><<<2048, 256, 0, stream>>>(outF, nullptr, w0, b0, ebuf, b);
    contract1_kernel<<<1024, 256, 0, stream>>>(ebuf, w2, b2, u1h);
    expand_kernel<1><<<2048, 256, 0, stream>>>(outF, y1h, w1, b1, ebuf, b);
    dwcontract2_kernel<<<256, 256, 0, stream>>>(ebuf, w3, b3, w4, b4, u2h);
    fftmix_kernel<<<512, 256, 0, stream>>>(u1h, u2h, kap1, kap2, outF, b);
  }
}

// Round 4
// 520.033 us; speedup vs baseline: 3.5692x; 3.5692x over previous
//
#include <hip/hip_runtime.h>

// Problem: B=4, C=64, H=W=256, D=16, C4=256, P=8.  HW=65536.
// Layouts: xn,y1,e are NHWC f16 (channel contiguous). out is NCHW f32.

typedef _Float16 f16;
typedef _Float16 f16x2 __attribute__((ext_vector_type(2)));
typedef _Float16 f16x8 __attribute__((ext_vector_type(8)));
typedef float f32x4 __attribute__((ext_vector_type(4)));

__device__ __forceinline__ float gelu_f(float x) {
  // tanh-form GELU: x * sigmoid(1.5957691*(x + 0.044715 x^3)); |err vs erf| < 1e-3
  float u = 1.5957691216f * (x + 0.044715f * x * x * x);
  float t = exp2f(-1.4426950409f * u);
#if __has_builtin(__builtin_amdgcn_rcpf)
  return x * __builtin_amdgcn_rcpf(1.0f + t);
#else
  return x / (1.0f + t);
#endif
}

__device__ __forceinline__ float dot2f(f16x2 a, f16x2 b, float c) {
#if __has_builtin(__builtin_amdgcn_fdot2)
  return __builtin_amdgcn_fdot2(a, b, c, false);
#else
  return c + (float)a.x * (float)b.x + (float)a.y * (float)b.y;
#endif
}

// ---------------------------------------------------------------------------
// kappa: irfft2(rfft2(x)*fw) == circular conv with kappa (verified round 2).
// Output packed f16 pairs: kapP[cpair][idx] as u32 {c even, c odd}.
// ---------------------------------------------------------------------------
__global__ void build_kappa_kernel(const float* __restrict__ fw1,
                                   const float* __restrict__ fw2,
                                   unsigned short* __restrict__ kapP1,
                                   unsigned short* __restrict__ kapP2) {
  int which = blockIdx.x >> 6, c = blockIdx.x & 63;
  const float* fw = which ? fw2 : fw1;
  unsigned short* dst = which ? kapP2 : kapP1;
  int t = threadIdx.x, a = t >> 3, bb = t & 7;
  __shared__ float Wt[64];
  __shared__ float ct[8];
  if (t == 0) {
    const float r2 = 0.70710678118654752440f;
    ct[0] = 1.f; ct[1] = r2; ct[2] = 0.f; ct[3] = -r2;
    ct[4] = -1.f; ct[5] = -r2; ct[6] = 0.f; ct[7] = r2;
  }
  {
    int u = a, v = bb;
    Wt[t] = (v <= 4) ? fw[c * 40 + u * 5 + v]
                     : fw[c * 40 + ((8 - u) & 7) * 5 + (8 - v)];
  }
  __syncthreads();
  float acc = 0.f;
  for (int u = 0; u < 8; ++u)
    for (int v = 0; v < 8; ++v)
      acc += Wt[u * 8 + v] * ct[(u * a + v * bb) & 7];
  f16 hv = (f16)(acc * 0.015625f);
  dst[(c >> 1) * 128 + t * 2 + (c & 1)] = __builtin_bit_cast(unsigned short, hv);
}

// ---------------------------------------------------------------------------
// Pre-convert weights to f16 (+ dw weight/bias packed by 8-ce groups).
// ---------------------------------------------------------------------------
__global__ void preconv_kernel(const float* __restrict__ w0, const float* __restrict__ w1,
                               const float* __restrict__ w2, const float* __restrict__ w4,
                               const float* __restrict__ w3, const float* __restrict__ b3,
                               f16* __restrict__ W0h, f16* __restrict__ W1h,
                               f16* __restrict__ W2h, f16* __restrict__ W4h,
                               f16* __restrict__ w3pk, f16* __restrict__ b3pk) {
  int i = blockIdx.x * 256 + threadIdx.x;
  if (i < 16384) W0h[i] = (f16)w0[i];
  else if (i < 32768) W1h[i - 16384] = (f16)w1[i - 16384];
  else if (i < 49152) W2h[i - 32768] = (f16)w2[i - 32768];
  else if (i < 65536) W4h[i - 49152] = (f16)w4[i - 49152];
  else if (i < 67840) {
    int j = i - 65536;                 // [g][tap][k]: value = w3[(g*8+k)*9+tap]
    int g = j / 72, r = j % 72, tap = r >> 3, k = r & 7;
    w3pk[j] = (f16)w3[(g * 8 + k) * 9 + tap];
  } else if (i < 68096) {
    int k = i - 67840;
    b3pk[k] = (f16)b3[k];
  }
}

// ---------------------------------------------------------------------------
// LayerNorm over 64 channels per pixel.  x NCHW f32 -> xn NHWC f16 (per batch).
// ---------------------------------------------------------------------------
__global__ void __launch_bounds__(256) ln_kernel(const float* __restrict__ x,
                                                 const float* __restrict__ lnw,
                                                 const float* __restrict__ lnb,
                                                 f16* __restrict__ xn, int b) {
  int px = blockIdx.x * 256 + threadIdx.x;
  const float* xp = x + ((size_t)b << 22) + px;
  float v[64];
  float s = 0.f;
#pragma unroll
  for (int c = 0; c < 64; ++c) { v[c] = xp[(size_t)c << 16]; s += v[c]; }
  float mu = s * (1.f / 64.f), s2 = 0.f;
#pragma unroll
  for (int c = 0; c < 64; ++c) { float d = v[c] - mu; s2 += d * d; }
  float rstd = rsqrtf(s2 * (1.f / 64.f) + 1e-6f);
  f16* op = xn + (size_t)px * 64;
#pragma unroll
  for (int g = 0; g < 8; ++g) {
    f16x8 pk;
#pragma unroll
    for (int j = 0; j < 8; ++j) {
      int c = g * 8 + j;
      pk[j] = (f16)((v[c] - mu) * rstd * lnw[c] + lnb[c]);
    }
    *(f16x8*)(op + g * 8) = pk;
  }
}

// ---------------------------------------------------------------------------
// 3x3 dense conv 16ci->16co on xn c<16 -> y1 NHWC f16 (per batch).
// 16x16 tiles, grid 256.  Halo rows padded to 640 B so the XOR swizzle
// (max offset 624) stays inside the row -- 576-B pitch aliased (round-3 bug).
// ---------------------------------------------------------------------------
__global__ void __launch_bounds__(256) pconv_kernel(const f16* __restrict__ xn,
                                                    const float* __restrict__ pw,
                                                    const float* __restrict__ pb,
                                                    f16* __restrict__ y1) {
  __shared__ __align__(16) char halo[18 * 640];  // 18 rows x (18 cols x 32B + pad)
  __shared__ f16 wpk[2304];                      // [co][tap][ci]
  __shared__ float pbs[16];
  int t = threadIdx.x, blk = blockIdx.x;
  int h0 = (blk >> 4) << 4, w0 = (blk & 15) << 4;
  for (int i = t; i < 2304; i += 256) {
    int co = i / 144, r = i % 144, tap = r >> 4, ci = r & 15;
    wpk[i] = (f16)pw[co * 144 + ci * 9 + tap];
  }
  if (t < 16) pbs[t] = pb[t];
  for (int i = 0; i < 3; ++i) {
    int u = i * 256 + t;
    if (u < 648) {
      int hp = u >> 1, half = u & 1;
      int hr = hp / 18, hc = hp - hr * 18;
      int h = h0 - 1 + hr, w = w0 - 1 + hc;
      f16x8 v = {0, 0, 0, 0, 0, 0, 0, 0};
      if ((unsigned)h < 256u && (unsigned)w < 256u)
        v = *(const f16x8*)(xn + ((((size_t)h << 8)) + w) * 64 + half * 8);
      *(f16x8*)(halo + hr * 640 + ((hc * 32 + half * 16) ^ ((hr & 7) << 4))) = v;
    }
  }
  __syncthreads();
  int rl = t >> 4, cl = t & 15;
  float acc[16];
#pragma unroll
  for (int co = 0; co < 16; ++co) acc[co] = pbs[co];
#pragma unroll
  for (int ty = 0; ty < 3; ++ty)
#pragma unroll
    for (int tx = 0; tx < 3; ++tx) {
      int hr = rl + ty, hc = cl + tx, tap = ty * 3 + tx;
      f16x8 ld0 = *(const f16x8*)(halo + hr * 640 + ((hc * 32) ^ ((hr & 7) << 4)));
      f16x8 ld1 = *(const f16x8*)(halo + hr * 640 + ((hc * 32 + 16) ^ ((hr & 7) << 4)));
#pragma unroll
      for (int co = 0; co < 16; ++co) {
#pragma unroll
        for (int p = 0; p < 4; ++p) {
          f16x2 xp = {ld0[2 * p], ld0[2 * p + 1]};
          f16x2 wp = *(const f16x2*)&wpk[co * 144 + tap * 16 + 2 * p];
          acc[co] = dot2f(xp, wp, acc[co]);
        }
#pragma unroll
        for (int p = 0; p < 4; ++p) {
          f16x2 xp = {ld1[2 * p], ld1[2 * p + 1]};
          f16x2 wp = *(const f16x2*)&wpk[co * 144 + tap * 16 + 8 + 2 * p];
          acc[co] = dot2f(xp, wp, acc[co]);
        }
      }
    }
  size_t px = (((size_t)(h0 + rl)) << 8) + w0 + cl;
  f16x8 o0, o1;
#pragma unroll
  for (int j = 0; j < 8; ++j) { o0[j] = (f16)acc[j]; o1[j] = (f16)acc[8 + j]; }
  *(f16x8*)(y1 + px * 16) = o0;
  *(f16x8*)(y1 + px * 16 + 8) = o1;
}

// ---------------------------------------------------------------------------
// MFMA expand: e[px][ce] = gelu(xn[px][ci] . W[ce][ci] + b).  Per batch.
// Block: 128 px x 128 ce, K=64.  Grid 1024 = 512 strips x 2 ce-halves.
// ---------------------------------------------------------------------------
template <int BR2>
__global__ void __launch_bounds__(256) expand_kernel(
    const f16* __restrict__ xn, const f16* __restrict__ y1,
    const f16* __restrict__ Wh, const float* __restrict__ bias,
    f16* __restrict__ e) {
  __shared__ __align__(16) f16 As[8192];   // [128 px][64 ci] swizzled 128B rows
  __shared__ __align__(16) f16 Bs[8192];   // [128 ce][64 ci] swizzled
  int t = threadIdx.x, blk = blockIdx.x;
  int px0 = (blk >> 1) << 7, ceB = (blk & 1) << 7;
#pragma unroll
  for (int i = 0; i < 4; ++i) {
    int u = i * 256 + t, row = u >> 3, cb = (u & 7) << 4, ci0 = cb >> 1;
    f16x8 v;
    if (BR2 && ci0 < 16) v = *(const f16x8*)(y1 + (size_t)(px0 + row) * 16 + ci0);
    else                 v = *(const f16x8*)(xn + (size_t)(px0 + row) * 64 + ci0);
    *(f16x8*)((char*)As + row * 128 + (cb ^ ((row & 7) << 4))) = v;
  }
#pragma unroll
  for (int i = 0; i < 4; ++i) {
    int u = i * 256 + t, row = u >> 3, cb = (u & 7) << 4;
    f16x8 v = *(const f16x8*)(Wh + (size_t)(ceB + row) * 64 + (cb >> 1));
    *(f16x8*)((char*)Bs + row * 128 + (cb ^ ((row & 7) << 4))) = v;
  }
  __syncthreads();
  int l = t & 63, wv = t >> 6, lm = l & 15, kg = l >> 4;
  f32x4 acc[2][8];
#pragma unroll
  for (int a = 0; a < 2; ++a)
#pragma unroll
    for (int n = 0; n < 8; ++n) acc[a][n] = (f32x4){0.f, 0.f, 0.f, 0.f};
#pragma unroll
  for (int kk = 0; kk < 2; ++kk) {
    int kb = kk * 64 + kg * 16;
    f16x8 af[2];
#pragma unroll
    for (int mt = 0; mt < 2; ++mt) {
      int row = wv * 32 + mt * 16 + lm;
      af[mt] = *(const f16x8*)((char*)As + row * 128 + (kb ^ ((row & 7) << 4)));
    }
    f16x8 bf[8];
#pragma unroll
    for (int nt = 0; nt < 8; ++nt) {
      int row = nt * 16 + lm;
      bf[nt] = *(const f16x8*)((char*)Bs + row * 128 + (kb ^ ((row & 7) << 4)));
    }
#pragma unroll
    for (int mt = 0; mt < 2; ++mt)
#pragma unroll
      for (int nt = 0; nt < 8; ++nt)
        acc[mt][nt] = __builtin_amdgcn_mfma_f32_16x16x32_f16(af[mt], bf[nt], acc[mt][nt], 0, 0, 0);
  }
  float bz[8];
#pragma unroll
  for (int nt = 0; nt < 8; ++nt) bz[nt] = bias[ceB + nt * 16 + lm];
#pragma unroll
  for (int mt = 0; mt < 2; ++mt)
#pragma unroll
    for (int nt = 0; nt < 8; ++nt) {
      int ce = ceB + nt * 16 + lm;
      int pxb = px0 + wv * 32 + mt * 16 + kg * 4;
#pragma unroll
      for (int r = 0; r < 4; ++r) {
        float g = gelu_f(acc[mt][nt][r] + bz[nt]);
        e[(size_t)(pxb + r) * 256 + ce] = (f16)g;
      }
    }
}

// ---------------------------------------------------------------------------
// Contract1 (K=256 -> 64co) + bias + window-mix(kappa1) -> write out NCHW.
// Block: 8x16 spatial tile (2 windows).  Grid 512.  Per batch.
// ---------------------------------------------------------------------------
__global__ void __launch_bounds__(256) c1mix_kernel(
    const f16* __restrict__ e, const f16* __restrict__ W2h,
    const float* __restrict__ b2, const unsigned short* __restrict__ kapP,
    float* __restrict__ out, int b) {
  __shared__ __align__(16) f16 As[8192];          // A-chunk; reused as mix buffer
  __shared__ __align__(16) unsigned int kaps[2048];
  int t = threadIdx.x, blk = blockIdx.x;
  int h0 = (blk >> 4) << 3, w0 = (blk & 15) << 4;
#pragma unroll
  for (int i = 0; i < 2; ++i) {
    int u = i * 256 + t;
    *(uint4*)(kaps + u * 4) = *(const uint4*)((const unsigned int*)kapP + u * 4);
  }
  int l = t & 63, wv = t >> 6, lm = l & 15, kg = l >> 4;
  f32x4 acc[2][4];
#pragma unroll
  for (int a = 0; a < 2; ++a)
#pragma unroll
    for (int n = 0; n < 4; ++n) acc[a][n] = (f32x4){0.f, 0.f, 0.f, 0.f};
  for (int kc = 0; kc < 4; ++kc) {
    if (kc) __syncthreads();
#pragma unroll
    for (int i = 0; i < 4; ++i) {
      int u = i * 256 + t, row = u >> 3, cb = (u & 7) << 4;
      int rl = row >> 4, cl = row & 15;
      size_t px = (((size_t)(h0 + rl)) << 8) + w0 + cl;
      f16x8 v = *(const f16x8*)(e + px * 256 + kc * 64 + (cb >> 1));
      *(f16x8*)((char*)As + row * 128 + (cb ^ ((row & 7) << 4))) = v;
    }
    __syncthreads();
#pragma unroll
    for (int kk = 0; kk < 2; ++kk) {
      int kb = kk * 64 + kg * 16;
      f16x8 af[2];
#pragma unroll
      for (int mt = 0; mt < 2; ++mt) {
        int row = wv * 32 + mt * 16 + lm;
        af[mt] = *(const f16x8*)((char*)As + row * 128 + (kb ^ ((row & 7) << 4)));
      }
      f16x8 bf[4];
#pragma unroll
      for (int nt = 0; nt < 4; ++nt) {
        int co = nt * 16 + lm;
        bf[nt] = *(const f16x8*)(W2h + (size_t)co * 256 + kc * 64 + kk * 32 + kg * 8);
      }
#pragma unroll
      for (int mt = 0; mt < 2; ++mt)
#pragma unroll
        for (int nt = 0; nt < 4; ++nt)
          acc[mt][nt] = __builtin_amdgcn_mfma_f32_16x16x32_f16(af[mt], bf[nt], acc[mt][nt], 0, 0, 0);
    }
  }
  __syncthreads();
  float bz[4];
#pragma unroll
  for (int nt = 0; nt < 4; ++nt) bz[nt] = b2[nt * 16 + lm];
#pragma unroll
  for (int mt = 0; mt < 2; ++mt)
#pragma unroll
    for (int nt = 0; nt < 4; ++nt) {
      int c = nt * 16 + lm;
#pragma unroll
      for (int r = 0; r < 4; ++r) {
        int m = wv * 32 + mt * 16 + kg * 4 + r;
        *(f16*)((char*)As + m * 128 + ((c * 2) ^ ((m & 7) << 4))) =
            (f16)(acc[mt][nt][r] + bz[nt]);
      }
    }
  __syncthreads();
  int win = wv >> 1, ch = wv & 1, s = l >> 3, tq = l & 7;
  int pxm = s * 16 + win * 8 + tq;
  int idxb[64];
#pragma unroll
  for (int j = 0; j < 64; ++j)
    idxb[j] = ((((s - (j >> 3)) & 7) << 3) | ((tq - (j & 7)) & 7)) << 2;
  for (int cp = 0; cp < 16; ++cp) {
    int cpair = ch * 16 + cp;
    unsigned int val = *(const unsigned int*)((char*)As + pxm * 128 + ((cpair << 2) ^ ((pxm & 7) << 4)));
    f16x2 a2 = {0, 0};
#pragma unroll
    for (int j = 0; j < 64; ++j) {
      unsigned int kv = *(const unsigned int*)((const char*)kaps + cpair * 256 + idxb[j]);
      unsigned int bv = (unsigned int)__builtin_amdgcn_readlane((int)val, j);
      a2 += __builtin_bit_cast(f16x2, bv) * __builtin_bit_cast(f16x2, kv);
    }
    int h = h0 + s, w = w0 + win * 8 + tq;
    size_t o0 = (((size_t)(b * 64 + cpair * 2)) << 16) + (h << 8) + w;
    out[o0] = (float)a2.x;
    out[o0 + 65536] = (float)a2.y;
  }
}

// ---------------------------------------------------------------------------
// dw3x3+gelu (producer) + contract2 (K=256) + b4 + mix(kappa2) -> out += .
// Same tile geometry as c1mix.  Grid 512.  Per batch.
// ---------------------------------------------------------------------------
__global__ void __launch_bounds__(256) c2mix_kernel(
    const f16* __restrict__ e, const f16* __restrict__ W4h,
    const float* __restrict__ b4, const unsigned short* __restrict__ kapP,
    const f16* __restrict__ w3pk, const f16* __restrict__ b3pk,
    float* __restrict__ out, int b) {
  __shared__ __align__(16) f16 halo[184 * 64];    // [10x18 px][64 ce] swizzled
  __shared__ __align__(16) f16 As[8192];
  __shared__ __align__(16) unsigned int kaps[2048];
  __shared__ __align__(16) f16 w3s[2304];
  __shared__ __align__(16) f16 b3s[256];
  int t = threadIdx.x, blk = blockIdx.x;
  int h0 = (blk >> 4) << 3, w0 = (blk & 15) << 4;
#pragma unroll
  for (int i = 0; i < 2; ++i) {
    int u = i * 256 + t;
    *(uint4*)(kaps + u * 4) = *(const uint4*)((const unsigned int*)kapP + u * 4);
  }
  for (int i = t; i < 288; i += 256)               // round-3 bug: was single pass
    *(f16x8*)(w3s + i * 8) = *(const f16x8*)(w3pk + i * 8);
  if (t < 32) *(f16x8*)(b3s + t * 8) = *(const f16x8*)(b3pk + t * 8);
  int l = t & 63, wv = t >> 6, lm = l & 15, kg = l >> 4;
  int pxl = t & 127, chh = t >> 7, rl = pxl >> 4, cl = pxl & 15;
  f32x4 acc[2][4];
#pragma unroll
  for (int a = 0; a < 2; ++a)
#pragma unroll
    for (int n = 0; n < 4; ++n) acc[a][n] = (f32x4){0.f, 0.f, 0.f, 0.f};
  for (int kc = 0; kc < 4; ++kc) {
    if (kc) __syncthreads();
    for (int i = 0; i < 6; ++i) {
      int u = i * 256 + t;
      if (u < 1440) {
        int hp = u >> 3, cb = (u & 7) << 4;
        int hr = hp / 18, hc = hp - hr * 18;
        int h = h0 - 1 + hr, w = w0 - 1 + hc;
        f16x8 v = {0, 0, 0, 0, 0, 0, 0, 0};
        if ((unsigned)h < 256u && (unsigned)w < 256u)
          v = *(const f16x8*)(e + ((((size_t)h << 8)) + w) * 256 + kc * 64 + (cb >> 1));
        *(f16x8*)((char*)halo + hp * 128 + (cb ^ ((hp & 7) << 4))) = v;
      }
    }
    __syncthreads();
#pragma unroll
    for (int c8 = 0; c8 < 4; ++c8) {
      int ceL = chh * 32 + c8 * 8;
      int ceG = kc * 64 + ceL, g = ceG >> 3;
      f16x8 a8 = *(const f16x8*)(b3s + ceG);
#pragma unroll
      for (int ty = 0; ty < 3; ++ty)
#pragma unroll
        for (int tx = 0; tx < 3; ++tx) {
          int hp = (rl + ty) * 18 + (cl + tx);
          f16x8 xv = *(const f16x8*)((char*)halo + hp * 128 + ((ceL * 2) ^ ((hp & 7) << 4)));
          f16x8 wv8 = *(const f16x8*)(w3s + g * 72 + (ty * 3 + tx) * 8);
          a8 += xv * wv8;
        }
      f16x8 r8;
#pragma unroll
      for (int j2 = 0; j2 < 8; ++j2) r8[j2] = (f16)gelu_f((float)a8[j2]);
      *(f16x8*)((char*)As + pxl * 128 + ((ceL * 2) ^ ((pxl & 7) << 4))) = r8;
    }
    __syncthreads();
#pragma unroll
    for (int kk = 0; kk < 2; ++kk) {
      int kb = kk * 64 + kg * 16;
      f16x8 af[2];
#pragma unroll
      for (int mt = 0; mt < 2; ++mt) {
        int row = wv * 32 + mt * 16 + lm;
        af[mt] = *(const f16x8*)((char*)As + row * 128 + (kb ^ ((row & 7) << 4)));
      }
      f16x8 bf[4];
#pragma unroll
      for (int nt = 0; nt < 4; ++nt) {
        int co = nt * 16 + lm;
        bf[nt] = *(const f16x8*)(W4h + (size_t)co * 256 + kc * 64 + kk * 32 + kg * 8);
      }
#pragma unroll
      for (int mt = 0; mt < 2; ++mt)
#pragma unroll
        for (int nt = 0; nt < 4; ++nt)
          acc[mt][nt] = __builtin_amdgcn_mfma_f32_16x16x32_f16(af[mt], bf[nt], acc[mt][nt], 0, 0, 0);
    }
  }
  __syncthreads();
  float bz[4];
#pragma unroll
  for (int nt = 0; nt < 4; ++nt) bz[nt] = b4[nt * 16 + lm];
#pragma unroll
  for (int mt = 0; mt < 2; ++mt)
#pragma unroll
    for (int nt = 0; nt < 4; ++nt) {
      int c = nt * 16 + lm;
#pragma unroll
      for (int r = 0; r < 4; ++r) {
        int m = wv * 32 + mt * 16 + kg * 4 + r;
        *(f16*)((char*)As + m * 128 + ((c * 2) ^ ((m & 7) << 4))) =
            (f16)(acc[mt][nt][r] + bz[nt]);
      }
    }
  __syncthreads();
  int win = wv >> 1, ch = wv & 1, s = l >> 3, tq = l & 7;
  int pxm = s * 16 + win * 8 + tq;
  int idxb[64];
#pragma unroll
  for (int j = 0; j < 64; ++j)
    idxb[j] = ((((s - (j >> 3)) & 7) << 3) | ((tq - (j & 7)) & 7)) << 2;
  for (int cp = 0; cp < 16; ++cp) {
    int cpair = ch * 16 + cp;
    unsigned int val = *(const unsigned int*)((char*)As + pxm * 128 + ((cpair << 2) ^ ((pxm & 7) << 4)));
    f16x2 a2 = {0, 0};
#pragma unroll
    for (int j = 0; j < 64; ++j) {
      unsigned int kv = *(const unsigned int*)((const char*)kaps + cpair * 256 + idxb[j]);
      unsigned int bv = (unsigned int)__builtin_amdgcn_readlane((int)val, j);
      a2 += __builtin_bit_cast(f16x2, bv) * __builtin_bit_cast(f16x2, kv);
    }
    int h = h0 + s, w = w0 + win * 8 + tq;
    size_t o0 = (((size_t)(b * 64 + cpair * 2)) << 16) + (h << 8) + w;
    out[o0] += (float)a2.x;
    out[o0 + 65536] += (float)a2.y;
  }
}

// ---------------------------------------------------------------------------
__global__ void diag_kernel(float* __restrict__ out, float code, int n) {
  int i = blockIdx.x * 256 + threadIdx.x;
  for (int p = i; p < n; p += 256 * 4096) out[p] = (p == 0) ? code : 0.f;
}

// ---------------------------------------------------------------------------
extern "C" void kernel_launch(void* const* d_in, const int* in_sizes, int n_in,
                              void* d_out, int out_size, void* d_ws,
                              size_t ws_size, hipStream_t stream) {
  const float* x       = (const float*)d_in[0];
  const float* ln_w    = (const float*)d_in[1];
  const float* ln_b    = (const float*)d_in[2];
  const float* pconv_w = (const float*)d_in[3];
  const float* pconv_b = (const float*)d_in[4];
  const float* w0      = (const float*)d_in[5];
  const float* b0      = (const float*)d_in[6];
  const float* w1      = (const float*)d_in[7];
  const float* b1      = (const float*)d_in[8];
  const float* w2      = (const float*)d_in[9];
  const float* b2      = (const float*)d_in[10];
  const float* w3      = (const float*)d_in[11];
  const float* b3      = (const float*)d_in[12];
  const float* w4      = (const float*)d_in[13];
  const float* b4      = (const float*)d_in[14];
  const float* fftw1   = (const float*)d_in[15];
  const float* fftw2   = (const float*)d_in[16];

  const size_t OFF_KAP1 = 0;           // 8 KB (packed f16 pairs)
  const size_t OFF_KAP2 = 8192;
  const size_t OFF_W0H  = 16384;       // 32 KB
  const size_t OFF_W1H  = 49152;
  const size_t OFF_W2H  = 81920;
  const size_t OFF_W4H  = 114688;
  const size_t OFF_W3PK = 147456;      // 4608 B
  const size_t OFF_B3PK = 152064;      // 512 B
  const size_t OFF_XN   = 152576;      // f16 [65536][64] = 8 MB (per batch)
  const size_t OFF_Y1   = OFF_XN + 8388608ull;   // f16 [65536][16] = 2 MB
  const size_t OFF_E    = OFF_Y1 + 2097152ull;   // f16 [65536][256] = 32 MB
  const size_t WS_NEED  = OFF_E + 33554432ull;   // ~42.1 MB

  float* outF = (float*)d_out;
  if (ws_size < WS_NEED) {
    diag_kernel<<<4096, 256, 0, stream>>>(outF, 1000.0f + (float)(ws_size >> 20), 16777216);
    return;
  }
  char* ws = (char*)d_ws;
  unsigned short* kapP1 = (unsigned short*)(ws + OFF_KAP1);
  unsigned short* kapP2 = (unsigned short*)(ws + OFF_KAP2);
  f16* W0h  = (f16*)(ws + OFF_W0H);
  f16* W1h  = (f16*)(ws + OFF_W1H);
  f16* W2h  = (f16*)(ws + OFF_W2H);
  f16* W4h  = (f16*)(ws + OFF_W4H);
  f16* w3pk = (f16*)(ws + OFF_W3PK);
  f16* b3pk = (f16*)(ws + OFF_B3PK);
  f16* XN   = (f16*)(ws + OFF_XN);
  f16* Y1   = (f16*)(ws + OFF_Y1);
  f16* E    = (f16*)(ws + OFF_E);

  build_kappa_kernel<<<128, 64, 0, stream>>>(fftw1, fftw2, kapP1, kapP2);
  preconv_kernel<<<266, 256, 0, stream>>>(w0, w1, w2, w4, w3, b3,
                                          W0h, W1h, W2h, W4h, w3pk, b3pk);
  for (int b = 0; b < 4; ++b) {
    ln_kernel<<<256, 256, 0, stream>>>(x, ln_w, ln_b, XN, b);
    pconv_kernel<<<256, 256, 0, stream>>>(XN, pconv_w, pconv_b, Y1);
    expand_kernel<0><<<1024, 256, 0, stream>>>(XN, Y1, W0h, b0, E);
    c1mix_kernel<<<512, 256, 0, stream>>>(E, W2h, b2, kapP1, outF, b);
    expand_kernel<1><<<1024, 256, 0, stream>>>(XN, Y1, W1h, b1, E);
    c2mix_kernel<<<512, 256, 0, stream>>>(E, W4h, b4, kapP2, w3pk, b3pk, outF, b);
  }
}

// Round 5
// 508.478 us; speedup vs baseline: 3.6503x; 1.0227x over previous
//
#include <hip/hip_runtime.h>

// Problem: B=4, C=64, H=W=256, D=16, C4=256, P=8.  HW=65536.
// Layouts: xn,y1,e NHWC f16 (channel contiguous); u1,u2 f16 [c][px] planes;
// out NCHW f32.

typedef _Float16 f16;
typedef _Float16 f16x2 __attribute__((ext_vector_type(2)));
typedef _Float16 f16x8 __attribute__((ext_vector_type(8)));
typedef float f32x4 __attribute__((ext_vector_type(4)));

__device__ __forceinline__ float gelu_f(float x) {
  // tanh-form GELU; |err vs erf| < 1e-3
  float u = 1.5957691216f * (x + 0.044715f * x * x * x);
  float t = exp2f(-1.4426950409f * u);
#if __has_builtin(__builtin_amdgcn_rcpf)
  return x * __builtin_amdgcn_rcpf(1.0f + t);
#else
  return x / (1.0f + t);
#endif
}

__device__ __forceinline__ float dot2f(f16x2 a, f16x2 b, float c) {
#if __has_builtin(__builtin_amdgcn_fdot2)
  return __builtin_amdgcn_fdot2(a, b, c, false);
#else
  return c + (float)a.x * (float)b.x + (float)a.y * (float)b.y;
#endif
}

// ---------------------------------------------------------------------------
// kappa: irfft2(rfft2(x)*fw) == circular conv with kappa (verified round 2).
// f32 out: kap[c][64].
// ---------------------------------------------------------------------------
__global__ void build_kappa_kernel(const float* __restrict__ fw1,
                                   const float* __restrict__ fw2,
                                   float* __restrict__ kap1,
                                   float* __restrict__ kap2) {
  int which = blockIdx.x >> 6, c = blockIdx.x & 63;
  const float* fw = which ? fw2 : fw1;
  float* kap = which ? kap2 : kap1;
  int t = threadIdx.x, a = t >> 3, bb = t & 7;
  __shared__ float Wt[64];
  __shared__ float ct[8];
  if (t == 0) {
    const float r2 = 0.70710678118654752440f;
    ct[0] = 1.f; ct[1] = r2; ct[2] = 0.f; ct[3] = -r2;
    ct[4] = -1.f; ct[5] = -r2; ct[6] = 0.f; ct[7] = r2;
  }
  {
    int u = a, v = bb;
    Wt[t] = (v <= 4) ? fw[c * 40 + u * 5 + v]
                     : fw[c * 40 + ((8 - u) & 7) * 5 + (8 - v)];
  }
  __syncthreads();
  float acc = 0.f;
  for (int u = 0; u < 8; ++u)
    for (int v = 0; v < 8; ++v)
      acc += Wt[u * 8 + v] * ct[(u * a + v * bb) & 7];
  kap[c * 64 + t] = acc * 0.015625f;
}

// ---------------------------------------------------------------------------
// Pre-convert weights to f16 (+ dw weight/bias packed by 8-ce groups).
// ---------------------------------------------------------------------------
__global__ void preconv_kernel(const float* __restrict__ w0, const float* __restrict__ w1,
                               const float* __restrict__ w2, const float* __restrict__ w4,
                               const float* __restrict__ w3, const float* __restrict__ b3,
                               f16* __restrict__ W0h, f16* __restrict__ W1h,
                               f16* __restrict__ W2h, f16* __restrict__ W4h,
                               f16* __restrict__ w3pk, f16* __restrict__ b3pk) {
  int i = blockIdx.x * 256 + threadIdx.x;
  if (i < 16384) W0h[i] = (f16)w0[i];
  else if (i < 32768) W1h[i - 16384] = (f16)w1[i - 16384];
  else if (i < 49152) W2h[i - 32768] = (f16)w2[i - 32768];
  else if (i < 65536) W4h[i - 49152] = (f16)w4[i - 49152];
  else if (i < 67840) {
    int j = i - 65536;                 // [g][tap][k]: value = w3[(g*8+k)*9+tap]
    int g = j / 72, r = j % 72, tap = r >> 3, k = r & 7;
    w3pk[j] = (f16)w3[(g * 8 + k) * 9 + tap];
  } else if (i < 68096) {
    int k = i - 67840;
    b3pk[k] = (f16)b3[k];
  }
}

// ---------------------------------------------------------------------------
// LayerNorm over 64 channels per pixel.  x NCHW f32 -> xn NHWC f16 (per batch).
// ---------------------------------------------------------------------------
__global__ void __launch_bounds__(256) ln_kernel(const float* __restrict__ x,
                                                 const float* __restrict__ lnw,
                                                 const float* __restrict__ lnb,
                                                 f16* __restrict__ xn, int b) {
  int px = blockIdx.x * 256 + threadIdx.x;
  const float* xp = x + ((size_t)b << 22) + px;
  float v[64];
  float s = 0.f;
#pragma unroll
  for (int c = 0; c < 64; ++c) { v[c] = xp[(size_t)c << 16]; s += v[c]; }
  float mu = s * (1.f / 64.f), s2 = 0.f;
#pragma unroll
  for (int c = 0; c < 64; ++c) { float d = v[c] - mu; s2 += d * d; }
  float rstd = rsqrtf(s2 * (1.f / 64.f) + 1e-6f);
  f16* op = xn + (size_t)px * 64;
#pragma unroll
  for (int g = 0; g < 8; ++g) {
    f16x8 pk;
#pragma unroll
    for (int j = 0; j < 8; ++j) {
      int c = g * 8 + j;
      pk[j] = (f16)((v[c] - mu) * rstd * lnw[c] + lnb[c]);
    }
    *(f16x8*)(op + g * 8) = pk;
  }
}

// ---------------------------------------------------------------------------
// 3x3 dense conv 16ci->16co on xn c<16 -> y1 NHWC f16 (per batch).
// 16x16 tiles, grid 256.  Halo rows padded to 640 B (swizzle-safe).
// ---------------------------------------------------------------------------
__global__ void __launch_bounds__(256) pconv_kernel(const f16* __restrict__ xn,
                                                    const float* __restrict__ pw,
                                                    const float* __restrict__ pb,
                                                    f16* __restrict__ y1) {
  __shared__ __align__(16) char halo[18 * 640];
  __shared__ f16 wpk[2304];                      // [co][tap][ci]
  __shared__ float pbs[16];
  int t = threadIdx.x, blk = blockIdx.x;
  int h0 = (blk >> 4) << 4, w0 = (blk & 15) << 4;
  for (int i = t; i < 2304; i += 256) {
    int co = i / 144, r = i % 144, tap = r >> 4, ci = r & 15;
    wpk[i] = (f16)pw[co * 144 + ci * 9 + tap];
  }
  if (t < 16) pbs[t] = pb[t];
  for (int i = 0; i < 3; ++i) {
    int u = i * 256 + t;
    if (u < 648) {
      int hp = u >> 1, half = u & 1;
      int hr = hp / 18, hc = hp - hr * 18;
      int h = h0 - 1 + hr, w = w0 - 1 + hc;
      f16x8 v = {0, 0, 0, 0, 0, 0, 0, 0};
      if ((unsigned)h < 256u && (unsigned)w < 256u)
        v = *(const f16x8*)(xn + ((((size_t)h << 8)) + w) * 64 + half * 8);
      *(f16x8*)(halo + hr * 640 + ((hc * 32 + half * 16) ^ ((hr & 7) << 4))) = v;
    }
  }
  __syncthreads();
  int rl = t >> 4, cl = t & 15;
  float acc[16];
#pragma unroll
  for (int co = 0; co < 16; ++co) acc[co] = pbs[co];
#pragma unroll
  for (int ty = 0; ty < 3; ++ty)
#pragma unroll
    for (int tx = 0; tx < 3; ++tx) {
      int hr = rl + ty, hc = cl + tx, tap = ty * 3 + tx;
      f16x8 ld0 = *(const f16x8*)(halo + hr * 640 + ((hc * 32) ^ ((hr & 7) << 4)));
      f16x8 ld1 = *(const f16x8*)(halo + hr * 640 + ((hc * 32 + 16) ^ ((hr & 7) << 4)));
#pragma unroll
      for (int co = 0; co < 16; ++co) {
#pragma unroll
        for (int p = 0; p < 4; ++p) {
          f16x2 xp = {ld0[2 * p], ld0[2 * p + 1]};
          f16x2 wp = *(const f16x2*)&wpk[co * 144 + tap * 16 + 2 * p];
          acc[co] = dot2f(xp, wp, acc[co]);
        }
#pragma unroll
        for (int p = 0; p < 4; ++p) {
          f16x2 xp = {ld1[2 * p], ld1[2 * p + 1]};
          f16x2 wp = *(const f16x2*)&wpk[co * 144 + tap * 16 + 8 + 2 * p];
          acc[co] = dot2f(xp, wp, acc[co]);
        }
      }
    }
  size_t px = (((size_t)(h0 + rl)) << 8) + w0 + cl;
  f16x8 o0, o1;
#pragma unroll
  for (int j = 0; j < 8; ++j) { o0[j] = (f16)acc[j]; o1[j] = (f16)acc[8 + j]; }
  *(f16x8*)(y1 + px * 16) = o0;
  *(f16x8*)(y1 + px * 16 + 8) = o1;
}

// ---------------------------------------------------------------------------
// MFMA expand: e[px][ce] = gelu(xn[px][ci] . W[ce][ci] + b).  Per batch.
// Block: 128 px x 128 ce, K=64.  Grid 1024 = 512 strips x 2 ce-halves.
// ---------------------------------------------------------------------------
template <int BR2>
__global__ void __launch_bounds__(256) expand_kernel(
    const f16* __restrict__ xn, const f16* __restrict__ y1,
    const f16* __restrict__ Wh, const float* __restrict__ bias,
    f16* __restrict__ e) {
  __shared__ __align__(16) f16 As[8192];   // [128 px][64 ci] swizzled 128B rows
  __shared__ __align__(16) f16 Bs[8192];   // [128 ce][64 ci] swizzled
  int t = threadIdx.x, blk = blockIdx.x;
  int px0 = (blk >> 1) << 7, ceB = (blk & 1) << 7;
#pragma unroll
  for (int i = 0; i < 4; ++i) {
    int u = i * 256 + t, row = u >> 3, cb = (u & 7) << 4, ci0 = cb >> 1;
    f16x8 v;
    if (BR2 && ci0 < 16) v = *(const f16x8*)(y1 + (size_t)(px0 + row) * 16 + ci0);
    else                 v = *(const f16x8*)(xn + (size_t)(px0 + row) * 64 + ci0);
    *(f16x8*)((char*)As + row * 128 + (cb ^ ((row & 7) << 4))) = v;
  }
#pragma unroll
  for (int i = 0; i < 4; ++i) {
    int u = i * 256 + t, row = u >> 3, cb = (u & 7) << 4;
    f16x8 v = *(const f16x8*)(Wh + (size_t)(ceB + row) * 64 + (cb >> 1));
    *(f16x8*)((char*)Bs + row * 128 + (cb ^ ((row & 7) << 4))) = v;
  }
  __syncthreads();
  int l = t & 63, wv = t >> 6, lm = l & 15, kg = l >> 4;
  f32x4 acc[2][8];
#pragma unroll
  for (int a = 0; a < 2; ++a)
#pragma unroll
    for (int n = 0; n < 8; ++n) acc[a][n] = (f32x4){0.f, 0.f, 0.f, 0.f};
#pragma unroll
  for (int kk = 0; kk < 2; ++kk) {
    int kb = kk * 64 + kg * 16;
    f16x8 af[2];
#pragma unroll
    for (int mt = 0; mt < 2; ++mt) {
      int row = wv * 32 + mt * 16 + lm;
      af[mt] = *(const f16x8*)((char*)As + row * 128 + (kb ^ ((row & 7) << 4)));
    }
    f16x8 bf[8];
#pragma unroll
    for (int nt = 0; nt < 8; ++nt) {
      int row = nt * 16 + lm;
      bf[nt] = *(const f16x8*)((char*)Bs + row * 128 + (kb ^ ((row & 7) << 4)));
    }
#pragma unroll
    for (int mt = 0; mt < 2; ++mt)
#pragma unroll
      for (int nt = 0; nt < 8; ++nt)
        acc[mt][nt] = __builtin_amdgcn_mfma_f32_16x16x32_f16(af[mt], bf[nt], acc[mt][nt], 0, 0, 0);
  }
  float bz[8];
#pragma unroll
  for (int nt = 0; nt < 8; ++nt) bz[nt] = bias[ceB + nt * 16 + lm];
#pragma unroll
  for (int mt = 0; mt < 2; ++mt)
#pragma unroll
    for (int nt = 0; nt < 8; ++nt) {
      int ce = ceB + nt * 16 + lm;
      int pxb = px0 + wv * 32 + mt * 16 + kg * 4;
#pragma unroll
      for (int r = 0; r < 4; ++r) {
        float g = gelu_f(acc[mt][nt][r] + bz[nt]);
        e[(size_t)(pxb + r) * 256 + ce] = (f16)g;
      }
    }
}

// ---------------------------------------------------------------------------
// Contract1: u1[co][px] = e[px][:] . W2[co][:] + b2.  Strip of 128 px.
// Grid 512.  Per batch.
// ---------------------------------------------------------------------------
__global__ void __launch_bounds__(256) c1_kernel(
    const f16* __restrict__ e, const f16* __restrict__ W2h,
    const float* __restrict__ b2, f16* __restrict__ u1) {
  __shared__ __align__(16) f16 As[8192];
  int t = threadIdx.x;
  int px0 = blockIdx.x << 7;
  int l = t & 63, wv = t >> 6, lm = l & 15, kg = l >> 4;
  f32x4 acc[2][4];
#pragma unroll
  for (int a = 0; a < 2; ++a)
#pragma unroll
    for (int n = 0; n < 4; ++n) acc[a][n] = (f32x4){0.f, 0.f, 0.f, 0.f};
  for (int kc = 0; kc < 4; ++kc) {
    if (kc) __syncthreads();
#pragma unroll
    for (int i = 0; i < 4; ++i) {
      int u = i * 256 + t, row = u >> 3, cb = (u & 7) << 4;
      f16x8 v = *(const f16x8*)(e + (size_t)(px0 + row) * 256 + kc * 64 + (cb >> 1));
      *(f16x8*)((char*)As + row * 128 + (cb ^ ((row & 7) << 4))) = v;
    }
    __syncthreads();
#pragma unroll
    for (int kk = 0; kk < 2; ++kk) {
      int kb = kk * 64 + kg * 16;
      f16x8 af[2];
#pragma unroll
      for (int mt = 0; mt < 2; ++mt) {
        int row = wv * 32 + mt * 16 + lm;
        af[mt] = *(const f16x8*)((char*)As + row * 128 + (kb ^ ((row & 7) << 4)));
      }
      f16x8 bf[4];
#pragma unroll
      for (int nt = 0; nt < 4; ++nt) {
        int co = nt * 16 + lm;
        bf[nt] = *(const f16x8*)(W2h + (size_t)co * 256 + kc * 64 + kk * 32 + kg * 8);
      }
#pragma unroll
      for (int mt = 0; mt < 2; ++mt)
#pragma unroll
        for (int nt = 0; nt < 4; ++nt)
          acc[mt][nt] = __builtin_amdgcn_mfma_f32_16x16x32_f16(af[mt], bf[nt], acc[mt][nt], 0, 0, 0);
    }
  }
  __syncthreads();
#pragma unroll
  for (int mt = 0; mt < 2; ++mt)
#pragma unroll
    for (int nt = 0; nt < 4; ++nt) {
      int c = nt * 16 + lm;
      float bz = b2[c];
#pragma unroll
      for (int r = 0; r < 4; ++r) {
        int m = wv * 32 + mt * 16 + kg * 4 + r;
        *(f16*)((char*)As + m * 128 + ((c * 2) ^ ((m & 7) << 4))) =
            (f16)(acc[mt][nt][r] + bz);
      }
    }
  __syncthreads();
  int co = t >> 2, q = t & 3;
  f16x8 o[4];
#pragma unroll
  for (int i = 0; i < 32; ++i) {
    int m = q * 32 + i;
    o[i >> 3][i & 7] =
        *(const f16*)((char*)As + m * 128 + ((co * 2) ^ ((m & 7) << 4)));
  }
  f16* up = u1 + ((size_t)co << 16) + px0 + q * 32;
#pragma unroll
  for (int ss = 0; ss < 4; ++ss) *(f16x8*)(up + ss * 8) = o[ss];
}

// ---------------------------------------------------------------------------
// dw3x3+gelu (producer) + contract2 (K=256) + b4 -> u2[co][px].  8x16 tiles.
// Grid 512.  Per batch.
// ---------------------------------------------------------------------------
__global__ void __launch_bounds__(256) c2_kernel(
    const f16* __restrict__ e, const f16* __restrict__ W4h,
    const float* __restrict__ b4, const f16* __restrict__ w3pk,
    const f16* __restrict__ b3pk, f16* __restrict__ u2) {
  __shared__ __align__(16) f16 halo[184 * 64];    // [10x18 px][64 ce] swizzled
  __shared__ __align__(16) f16 As[8192];
  __shared__ __align__(16) f16 w3s[2304];
  __shared__ __align__(16) f16 b3s[256];
  int t = threadIdx.x, blk = blockIdx.x;
  int h0 = (blk >> 4) << 3, w0 = (blk & 15) << 4;
  for (int i = t; i < 288; i += 256)
    *(f16x8*)(w3s + i * 8) = *(const f16x8*)(w3pk + i * 8);
  if (t < 32) *(f16x8*)(b3s + t * 8) = *(const f16x8*)(b3pk + t * 8);
  int l = t & 63, wv = t >> 6, lm = l & 15, kg = l >> 4;
  int pxl = t & 127, chh = t >> 7, rl = pxl >> 4, cl = pxl & 15;
  f32x4 acc[2][4];
#pragma unroll
  for (int a = 0; a < 2; ++a)
#pragma unroll
    for (int n = 0; n < 4; ++n) acc[a][n] = (f32x4){0.f, 0.f, 0.f, 0.f};
  for (int kc = 0; kc < 4; ++kc) {
    if (kc) __syncthreads();
    for (int i = 0; i < 6; ++i) {
      int u = i * 256 + t;
      if (u < 1440) {
        int hp = u >> 3, cb = (u & 7) << 4;
        int hr = hp / 18, hc = hp - hr * 18;
        int h = h0 - 1 + hr, w = w0 - 1 + hc;
        f16x8 v = {0, 0, 0, 0, 0, 0, 0, 0};
        if ((unsigned)h < 256u && (unsigned)w < 256u)
          v = *(const f16x8*)(e + ((((size_t)h << 8)) + w) * 256 + kc * 64 + (cb >> 1));
        *(f16x8*)((char*)halo + hp * 128 + (cb ^ ((hp & 7) << 4))) = v;
      }
    }
    __syncthreads();
#pragma unroll
    for (int c8 = 0; c8 < 4; ++c8) {
      int ceL = chh * 32 + c8 * 8;
      int ceG = kc * 64 + ceL, g = ceG >> 3;
      f16x8 a8 = *(const f16x8*)(b3s + ceG);
#pragma unroll
      for (int ty = 0; ty < 3; ++ty)
#pragma unroll
        for (int tx = 0; tx < 3; ++tx) {
          int hp = (rl + ty) * 18 + (cl + tx);
          f16x8 xv = *(const f16x8*)((char*)halo + hp * 128 + ((ceL * 2) ^ ((hp & 7) << 4)));
          f16x8 wv8 = *(const f16x8*)(w3s + g * 72 + (ty * 3 + tx) * 8);
          a8 += xv * wv8;
        }
      f16x8 r8;
#pragma unroll
      for (int j2 = 0; j2 < 8; ++j2) r8[j2] = (f16)gelu_f((float)a8[j2]);
      *(f16x8*)((char*)As + pxl * 128 + ((ceL * 2) ^ ((pxl & 7) << 4))) = r8;
    }
    __syncthreads();
#pragma unroll
    for (int kk = 0; kk < 2; ++kk) {
      int kb = kk * 64 + kg * 16;
      f16x8 af[2];
#pragma unroll
      for (int mt = 0; mt < 2; ++mt) {
        int row = wv * 32 + mt * 16 + lm;
        af[mt] = *(const f16x8*)((char*)As + row * 128 + (kb ^ ((row & 7) << 4)));
      }
      f16x8 bf[4];
#pragma unroll
      for (int nt = 0; nt < 4; ++nt) {
        int co = nt * 16 + lm;
        bf[nt] = *(const f16x8*)(W4h + (size_t)co * 256 + kc * 64 + kk * 32 + kg * 8);
      }
#pragma unroll
      for (int mt = 0; mt < 2; ++mt)
#pragma unroll
        for (int nt = 0; nt < 4; ++nt)
          acc[mt][nt] = __builtin_amdgcn_mfma_f32_16x16x32_f16(af[mt], bf[nt], acc[mt][nt], 0, 0, 0);
    }
  }
  __syncthreads();
#pragma unroll
  for (int mt = 0; mt < 2; ++mt)
#pragma unroll
    for (int nt = 0; nt < 4; ++nt) {
      int c = nt * 16 + lm;
      float bz = b4[c];
#pragma unroll
      for (int r = 0; r < 4; ++r) {
        int m = wv * 32 + mt * 16 + kg * 4 + r;
        *(f16*)((char*)As + m * 128 + ((c * 2) ^ ((m & 7) << 4))) =
            (f16)(acc[mt][nt][r] + bz);
      }
    }
  __syncthreads();
  int co = t >> 2, q = t & 3;
  f16x8 o[4];
#pragma unroll
  for (int i = 0; i < 32; ++i) {
    int m = q * 32 + i;
    o[i >> 3][i & 7] =
        *(const f16*)((char*)As + m * 128 + ((co * 2) ^ ((m & 7) << 4)));
  }
  f16* up = u2 + ((size_t)co << 16) + (size_t)(h0 + 2 * q) * 256 + w0;
  *(f16x8*)(up) = o[0];
  *(f16x8*)(up + 8) = o[1];
  *(f16x8*)(up + 256) = o[2];
  *(f16x8*)(up + 256 + 8) = o[3];
}

// ---------------------------------------------------------------------------
// out = circconv8x8(u1,k1) + circconv8x8(u2,k2).  Wave = one c; lane = px in
// window; kp[64] packed (k1,k2) f16 pairs in VGPRs; 32 windows/wave via
// readlane + fdot2 (round-2 verified).  Grid 512 = C * 8 parts.  Per batch.
// ---------------------------------------------------------------------------
__global__ void __launch_bounds__(256) fftmix_kernel(
    const f16* __restrict__ u1, const f16* __restrict__ u2,
    const float* __restrict__ kap1, const float* __restrict__ kap2,
    float* __restrict__ out, int b) {
  int blk = blockIdx.x;           // 0..511
  int c = blk >> 3, part = blk & 7;
  int l = threadIdx.x & 63, wv = (threadIdx.x >> 6) & 3;
  int s = l >> 3, tq = l & 7;
  unsigned int kp[64];
#pragma unroll
  for (int j = 0; j < 64; ++j) {
    int idx = (((s - (j >> 3)) & 7) << 3) | ((tq - (j & 7)) & 7);
    f16 k1 = (f16)kap1[(c << 6) + idx];
    f16 k2 = (f16)kap2[(c << 6) + idx];
    kp[j] = (unsigned int)__builtin_bit_cast(unsigned short, k1) |
            ((unsigned int)__builtin_bit_cast(unsigned short, k2) << 16);
  }
  size_t cb = ((size_t)c) << 16;
  size_t obase = ((size_t)(b * 64 + c)) << 16;
  int win0 = part * 128 + wv * 32;
  for (int it = 0; it < 32; ++it) {
    int win = win0 + it;
    int wh = win >> 5, ww = win & 31;
    size_t pix = (size_t)((wh * 8 + s) << 8) + ww * 8 + tq;
    unsigned int pk =
        (unsigned int)__builtin_bit_cast(unsigned short, u1[cb + pix]) |
        ((unsigned int)__builtin_bit_cast(unsigned short, u2[cb + pix]) << 16);
    float acc = 0.f;
#pragma unroll
    for (int j = 0; j < 64; ++j) {
      unsigned int bc = (unsigned int)__builtin_amdgcn_readlane((int)pk, j);
      acc = dot2f(__builtin_bit_cast(f16x2, bc),
                  __builtin_bit_cast(f16x2, kp[j]), acc);
    }
    out[obase + pix] = acc;
  }
}

// ---------------------------------------------------------------------------
__global__ void diag_kernel(float* __restrict__ out, float code, int n) {
  int i = blockIdx.x * 256 + threadIdx.x;
  for (int p = i; p < n; p += 256 * 4096) out[p] = (p == 0) ? code : 0.f;
}

// ---------------------------------------------------------------------------
extern "C" void kernel_launch(void* const* d_in, const int* in_sizes, int n_in,
                              void* d_out, int out_size, void* d_ws,
                              size_t ws_size, hipStream_t stream) {
  const float* x       = (const float*)d_in[0];
  const float* ln_w    = (const float*)d_in[1];
  const float* ln_b    = (const float*)d_in[2];
  const float* pconv_w = (const float*)d_in[3];
  const float* pconv_b = (const float*)d_in[4];
  const float* w0      = (const float*)d_in[5];
  const float* b0      = (const float*)d_in[6];
  const float* w1      = (const float*)d_in[7];
  const float* b1      = (const float*)d_in[8];
  const float* w2      = (const float*)d_in[9];
  const float* b2      = (const float*)d_in[10];
  const float* w3      = (const float*)d_in[11];
  const float* b3      = (const float*)d_in[12];
  const float* w4      = (const float*)d_in[13];
  const float* b4      = (const float*)d_in[14];
  const float* fftw1   = (const float*)d_in[15];
  const float* fftw2   = (const float*)d_in[16];

  const size_t OFF_KAP1 = 0;                        // f32 [64][64] = 16 KB
  const size_t OFF_KAP2 = 16384;
  const size_t OFF_W0H  = 32768;                    // 32 KB each
  const size_t OFF_W1H  = 65536;
  const size_t OFF_W2H  = 98304;
  const size_t OFF_W4H  = 131072;
  const size_t OFF_W3PK = 163840;                   // 4608 B
  const size_t OFF_B3PK = 168448;                   // 512 B
  const size_t OFF_XN   = 168960;                   // f16 [65536][64] = 8 MB; u2 overlays
  const size_t OFF_Y1   = OFF_XN + 8388608ull;      // f16 [65536][16] = 2 MB
  const size_t OFF_E    = OFF_Y1 + 2097152ull;      // f16 [65536][256] = 32 MB
  const size_t OFF_U1   = OFF_E + 33554432ull;      // f16 [64][65536] = 8 MB
  const size_t WS_NEED  = OFF_U1 + 8388608ull;      // 52,597,760 B (< proven 58.75 MB)

  float* outF = (float*)d_out;
  if (ws_size < WS_NEED) {
    diag_kernel<<<4096, 256, 0, stream>>>(outF, 1000.0f + (float)(ws_size >> 20), 16777216);
    return;
  }
  char* ws = (char*)d_ws;
  float* kap1 = (float*)(ws + OFF_KAP1);
  float* kap2 = (float*)(ws + OFF_KAP2);
  f16* W0h  = (f16*)(ws + OFF_W0H);
  f16* W1h  = (f16*)(ws + OFF_W1H);
  f16* W2h  = (f16*)(ws + OFF_W2H);
  f16* W4h  = (f16*)(ws + OFF_W4H);
  f16* w3pk = (f16*)(ws + OFF_W3PK);
  f16* b3pk = (f16*)(ws + OFF_B3PK);
  f16* XN   = (f16*)(ws + OFF_XN);
  f16* U2   = (f16*)(ws + OFF_XN);   // overlays XN (xn dead after exp2)
  f16* Y1   = (f16*)(ws + OFF_Y1);
  f16* E    = (f16*)(ws + OFF_E);
  f16* U1   = (f16*)(ws + OFF_U1);

  build_kappa_kernel<<<128, 64, 0, stream>>>(fftw1, fftw2, kap1, kap2);
  preconv_kernel<<<266, 256, 0, stream>>>(w0, w1, w2, w4, w3, b3,
                                          W0h, W1h, W2h, W4h, w3pk, b3pk);
  for (int b = 0; b < 4; ++b) {
    ln_kernel<<<256, 256, 0, stream>>>(x, ln_w, ln_b, XN, b);
    pconv_kernel<<<256, 256, 0, stream>>>(XN, pconv_w, pconv_b, Y1);
    expand_kernel<0><<<1024, 256, 0, stream>>>(XN, Y1, W0h, b0, E);
    c1_kernel<<<512, 256, 0, stream>>>(E, W2h, b2, U1);
    expand_kernel<1><<<1024, 256, 0, stream>>>(XN, Y1, W1h, b1, E);
    c2_kernel<<<512, 256, 0, stream>>>(E, W4h, b4, w3pk, b3pk, U2);
    fftmix_kernel<<<512, 256, 0, stream>>>(U1, U2, kap1, kap2, outF, b);
  }
}

// Round 6
// 490.239 us; speedup vs baseline: 3.7861x; 1.0372x over previous
//
#include <hip/hip_runtime.h>

// Problem: B=4, C=64, H=W=256, D=16, C4=256, P=8.  HW=65536.
// Layouts: xn,y1,e NHWC f16 (channel contiguous); u1,u2 f16 [c][px] planes;
// out NCHW f32.

typedef _Float16 f16;
typedef _Float16 f16x2 __attribute__((ext_vector_type(2)));
typedef _Float16 f16x8 __attribute__((ext_vector_type(8)));
typedef float f32x4 __attribute__((ext_vector_type(4)));

__device__ __forceinline__ float gelu_f(float x) {
  // tanh-form GELU; |err vs erf| < 1e-3
  float u = 1.5957691216f * (x + 0.044715f * x * x * x);
  float t = exp2f(-1.4426950409f * u);
#if __has_builtin(__builtin_amdgcn_rcpf)
  return x * __builtin_amdgcn_rcpf(1.0f + t);
#else
  return x / (1.0f + t);
#endif
}

__device__ __forceinline__ float dot2f(f16x2 a, f16x2 b, float c) {
#if __has_builtin(__builtin_amdgcn_fdot2)
  return __builtin_amdgcn_fdot2(a, b, c, false);
#else
  return c + (float)a.x * (float)b.x + (float)a.y * (float)b.y;
#endif
}

// ---------------------------------------------------------------------------
// kappa: irfft2(rfft2(x)*fw) == circular conv with kappa (verified round 2).
// f32 out: kap[c][64].
// ---------------------------------------------------------------------------
__global__ void build_kappa_kernel(const float* __restrict__ fw1,
                                   const float* __restrict__ fw2,
                                   float* __restrict__ kap1,
                                   float* __restrict__ kap2) {
  int which = blockIdx.x >> 6, c = blockIdx.x & 63;
  const float* fw = which ? fw2 : fw1;
  float* kap = which ? kap2 : kap1;
  int t = threadIdx.x, a = t >> 3, bb = t & 7;
  __shared__ float Wt[64];
  __shared__ float ct[8];
  if (t == 0) {
    const float r2 = 0.70710678118654752440f;
    ct[0] = 1.f; ct[1] = r2; ct[2] = 0.f; ct[3] = -r2;
    ct[4] = -1.f; ct[5] = -r2; ct[6] = 0.f; ct[7] = r2;
  }
  {
    int u = a, v = bb;
    Wt[t] = (v <= 4) ? fw[c * 40 + u * 5 + v]
                     : fw[c * 40 + ((8 - u) & 7) * 5 + (8 - v)];
  }
  __syncthreads();
  float acc = 0.f;
  for (int u = 0; u < 8; ++u)
    for (int v = 0; v < 8; ++v)
      acc += Wt[u * 8 + v] * ct[(u * a + v * bb) & 7];
  kap[c * 64 + t] = acc * 0.015625f;
}

// ---------------------------------------------------------------------------
// Pre-convert weights to f16 (+ dw weight/bias packed by 8-ce groups).
// ---------------------------------------------------------------------------
__global__ void preconv_kernel(const float* __restrict__ w0, const float* __restrict__ w1,
                               const float* __restrict__ w2, const float* __restrict__ w4,
                               const float* __restrict__ w3, const float* __restrict__ b3,
                               f16* __restrict__ W0h, f16* __restrict__ W1h,
                               f16* __restrict__ W2h, f16* __restrict__ W4h,
                               f16* __restrict__ w3pk, f16* __restrict__ b3pk) {
  int i = blockIdx.x * 256 + threadIdx.x;
  if (i < 16384) W0h[i] = (f16)w0[i];
  else if (i < 32768) W1h[i - 16384] = (f16)w1[i - 16384];
  else if (i < 49152) W2h[i - 32768] = (f16)w2[i - 32768];
  else if (i < 65536) W4h[i - 49152] = (f16)w4[i - 49152];
  else if (i < 67840) {
    int j = i - 65536;                 // [g][tap][k]: value = w3[(g*8+k)*9+tap]
    int g = j / 72, r = j % 72, tap = r >> 3, k = r & 7;
    w3pk[j] = (f16)w3[(g * 8 + k) * 9 + tap];
  } else if (i < 68096) {
    int k = i - 67840;
    b3pk[k] = (f16)b3[k];
  }
}

// ---------------------------------------------------------------------------
// LayerNorm over 64 channels per pixel.  x NCHW f32 -> xn NHWC f16 (per batch).
// ---------------------------------------------------------------------------
__global__ void __launch_bounds__(256) ln_kernel(const float* __restrict__ x,
                                                 const float* __restrict__ lnw,
                                                 const float* __restrict__ lnb,
                                                 f16* __restrict__ xn, int b) {
  int px = blockIdx.x * 256 + threadIdx.x;
  const float* xp = x + ((size_t)b << 22) + px;
  float v[64];
  float s = 0.f;
#pragma unroll
  for (int c = 0; c < 64; ++c) { v[c] = xp[(size_t)c << 16]; s += v[c]; }
  float mu = s * (1.f / 64.f), s2 = 0.f;
#pragma unroll
  for (int c = 0; c < 64; ++c) { float d = v[c] - mu; s2 += d * d; }
  float rstd = rsqrtf(s2 * (1.f / 64.f) + 1e-6f);
  f16* op = xn + (size_t)px * 64;
#pragma unroll
  for (int g = 0; g < 8; ++g) {
    f16x8 pk;
#pragma unroll
    for (int j = 0; j < 8; ++j) {
      int c = g * 8 + j;
      pk[j] = (f16)((v[c] - mu) * rstd * lnw[c] + lnb[c]);
    }
    *(f16x8*)(op + g * 8) = pk;
  }
}

// ---------------------------------------------------------------------------
// 3x3 dense conv 16ci->16co on xn c<16 -> y1 NHWC f16 (per batch).
// 16x16 tiles, grid 256.  Halo rows padded to 640 B (swizzle-safe).
// ---------------------------------------------------------------------------
__global__ void __launch_bounds__(256) pconv_kernel(const f16* __restrict__ xn,
                                                    const float* __restrict__ pw,
                                                    const float* __restrict__ pb,
                                                    f16* __restrict__ y1) {
  __shared__ __align__(16) char halo[18 * 640];
  __shared__ f16 wpk[2304];                      // [co][tap][ci]
  __shared__ float pbs[16];
  int t = threadIdx.x, blk = blockIdx.x;
  int h0 = (blk >> 4) << 4, w0 = (blk & 15) << 4;
  for (int i = t; i < 2304; i += 256) {
    int co = i / 144, r = i % 144, tap = r >> 4, ci = r & 15;
    wpk[i] = (f16)pw[co * 144 + ci * 9 + tap];
  }
  if (t < 16) pbs[t] = pb[t];
  for (int i = 0; i < 3; ++i) {
    int u = i * 256 + t;
    if (u < 648) {
      int hp = u >> 1, half = u & 1;
      int hr = hp / 18, hc = hp - hr * 18;
      int h = h0 - 1 + hr, w = w0 - 1 + hc;
      f16x8 v = {0, 0, 0, 0, 0, 0, 0, 0};
      if ((unsigned)h < 256u && (unsigned)w < 256u)
        v = *(const f16x8*)(xn + ((((size_t)h << 8)) + w) * 64 + half * 8);
      *(f16x8*)(halo + hr * 640 + ((hc * 32 + half * 16) ^ ((hr & 7) << 4))) = v;
    }
  }
  __syncthreads();
  int rl = t >> 4, cl = t & 15;
  float acc[16];
#pragma unroll
  for (int co = 0; co < 16; ++co) acc[co] = pbs[co];
#pragma unroll
  for (int ty = 0; ty < 3; ++ty)
#pragma unroll
    for (int tx = 0; tx < 3; ++tx) {
      int hr = rl + ty, hc = cl + tx, tap = ty * 3 + tx;
      f16x8 ld0 = *(const f16x8*)(halo + hr * 640 + ((hc * 32) ^ ((hr & 7) << 4)));
      f16x8 ld1 = *(const f16x8*)(halo + hr * 640 + ((hc * 32 + 16) ^ ((hr & 7) << 4)));
#pragma unroll
      for (int co = 0; co < 16; ++co) {
#pragma unroll
        for (int p = 0; p < 4; ++p) {
          f16x2 xp = {ld0[2 * p], ld0[2 * p + 1]};
          f16x2 wp = *(const f16x2*)&wpk[co * 144 + tap * 16 + 2 * p];
          acc[co] = dot2f(xp, wp, acc[co]);
        }
#pragma unroll
        for (int p = 0; p < 4; ++p) {
          f16x2 xp = {ld1[2 * p], ld1[2 * p + 1]};
          f16x2 wp = *(const f16x2*)&wpk[co * 144 + tap * 16 + 8 + 2 * p];
          acc[co] = dot2f(xp, wp, acc[co]);
        }
      }
    }
  size_t px = (((size_t)(h0 + rl)) << 8) + w0 + cl;
  f16x8 o0, o1;
#pragma unroll
  for (int j = 0; j < 8; ++j) { o0[j] = (f16)acc[j]; o1[j] = (f16)acc[8 + j]; }
  *(f16x8*)(y1 + px * 16) = o0;
  *(f16x8*)(y1 + px * 16 + 8) = o1;
}

// ---------------------------------------------------------------------------
// Fused branch 1: u1[co][px] = (gelu(xn.W0+b0)).W2 + b2 for a 128-px strip.
// e-chunk lives only in LDS (no global round trip).  Grid 512.  Per batch.
// ---------------------------------------------------------------------------
__global__ void __launch_bounds__(256) b1_kernel(
    const f16* __restrict__ xn, const f16* __restrict__ W0h,
    const float* __restrict__ b0, const f16* __restrict__ W2h,
    const float* __restrict__ b2, f16* __restrict__ u1) {
  __shared__ __align__(16) f16 As[8192];   // xn strip [128 px][64 ci] swizzled
  __shared__ __align__(16) f16 Es[8192];   // e chunk [128 px][64 ce] swizzled
  int t = threadIdx.x;
  int px0 = blockIdx.x << 7;
#pragma unroll
  for (int i = 0; i < 4; ++i) {
    int u = i * 256 + t, row = u >> 3, cb = (u & 7) << 4;
    f16x8 v = *(const f16x8*)(xn + (size_t)(px0 + row) * 64 + (cb >> 1));
    *(f16x8*)((char*)As + row * 128 + (cb ^ ((row & 7) << 4))) = v;
  }
  __syncthreads();
  int l = t & 63, wv = t >> 6, lm = l & 15, kg = l >> 4;
  f32x4 uacc[2][4];
#pragma unroll
  for (int a = 0; a < 2; ++a)
#pragma unroll
    for (int n = 0; n < 4; ++n) uacc[a][n] = (f32x4){0.f, 0.f, 0.f, 0.f};
  for (int cc = 0; cc < 4; ++cc) {
    // --- expand chunk: e[128][64] = gelu(As . W0[cc*64..][..] + b0) ---
    f32x4 eacc[2][4];
#pragma unroll
    for (int a = 0; a < 2; ++a)
#pragma unroll
      for (int n = 0; n < 4; ++n) eacc[a][n] = (f32x4){0.f, 0.f, 0.f, 0.f};
#pragma unroll
    for (int kk = 0; kk < 2; ++kk) {
      int kb = kk * 64 + kg * 16;
      f16x8 af[2];
#pragma unroll
      for (int mt = 0; mt < 2; ++mt) {
        int row = wv * 32 + mt * 16 + lm;
        af[mt] = *(const f16x8*)((char*)As + row * 128 + (kb ^ ((row & 7) << 4)));
      }
      f16x8 bf[4];
#pragma unroll
      for (int nt = 0; nt < 4; ++nt) {
        int co = cc * 64 + nt * 16 + lm;
        bf[nt] = *(const f16x8*)(W0h + (size_t)co * 64 + kk * 32 + kg * 8);
      }
#pragma unroll
      for (int mt = 0; mt < 2; ++mt)
#pragma unroll
        for (int nt = 0; nt < 4; ++nt)
          eacc[mt][nt] = __builtin_amdgcn_mfma_f32_16x16x32_f16(af[mt], bf[nt], eacc[mt][nt], 0, 0, 0);
    }
    if (cc) __syncthreads();   // prior contract reads of Es done
#pragma unroll
    for (int mt = 0; mt < 2; ++mt)
#pragma unroll
      for (int nt = 0; nt < 4; ++nt) {
        int c = nt * 16 + lm;
        float bz = b0[cc * 64 + c];
#pragma unroll
        for (int r = 0; r < 4; ++r) {
          int m = wv * 32 + mt * 16 + kg * 4 + r;
          *(f16*)((char*)Es + m * 128 + ((c * 2) ^ ((m & 7) << 4))) =
              (f16)gelu_f(eacc[mt][nt][r] + bz);
        }
      }
    __syncthreads();
    // --- contract partial: uacc += Es . W2[:, cc*64..] ---
#pragma unroll
    for (int kk = 0; kk < 2; ++kk) {
      int kb = kk * 64 + kg * 16;
      f16x8 af[2];
#pragma unroll
      for (int mt = 0; mt < 2; ++mt) {
        int row = wv * 32 + mt * 16 + lm;
        af[mt] = *(const f16x8*)((char*)Es + row * 128 + (kb ^ ((row & 7) << 4)));
      }
      f16x8 bf[4];
#pragma unroll
      for (int nt = 0; nt < 4; ++nt) {
        int co = nt * 16 + lm;
        bf[nt] = *(const f16x8*)(W2h + (size_t)co * 256 + cc * 64 + kk * 32 + kg * 8);
      }
#pragma unroll
      for (int mt = 0; mt < 2; ++mt)
#pragma unroll
        for (int nt = 0; nt < 4; ++nt)
          uacc[mt][nt] = __builtin_amdgcn_mfma_f32_16x16x32_f16(af[mt], bf[nt], uacc[mt][nt], 0, 0, 0);
    }
    __syncthreads();
  }
  // --- tail: uacc + b2 -> Es -> u1[co][px] (c1-proven pattern) ---
#pragma unroll
  for (int mt = 0; mt < 2; ++mt)
#pragma unroll
    for (int nt = 0; nt < 4; ++nt) {
      int c = nt * 16 + lm;
      float bz = b2[c];
#pragma unroll
      for (int r = 0; r < 4; ++r) {
        int m = wv * 32 + mt * 16 + kg * 4 + r;
        *(f16*)((char*)Es + m * 128 + ((c * 2) ^ ((m & 7) << 4))) =
            (f16)(uacc[mt][nt][r] + bz);
      }
    }
  __syncthreads();
  int co = t >> 2, q = t & 3;
  f16x8 o[4];
#pragma unroll
  for (int i = 0; i < 32; ++i) {
    int m = q * 32 + i;
    o[i >> 3][i & 7] =
        *(const f16*)((char*)Es + m * 128 + ((co * 2) ^ ((m & 7) << 4)));
  }
  f16* up = u1 + ((size_t)co << 16) + px0 + q * 32;
#pragma unroll
  for (int ss = 0; ss < 4; ++ss) *(f16x8*)(up + ss * 8) = o[ss];
}

// ---------------------------------------------------------------------------
// MFMA expand: e[px][ce] = gelu(xn[px][ci] . W[ce][ci] + b).  Per batch.
// Block: 128 px x 128 ce, K=64.  Grid 1024 = 512 strips x 2 ce-halves.
// ---------------------------------------------------------------------------
template <int BR2>
__global__ void __launch_bounds__(256) expand_kernel(
    const f16* __restrict__ xn, const f16* __restrict__ y1,
    const f16* __restrict__ Wh, const float* __restrict__ bias,
    f16* __restrict__ e) {
  __shared__ __align__(16) f16 As[8192];   // [128 px][64 ci] swizzled 128B rows
  __shared__ __align__(16) f16 Bs[8192];   // [128 ce][64 ci] swizzled
  int t = threadIdx.x, blk = blockIdx.x;
  int px0 = (blk >> 1) << 7, ceB = (blk & 1) << 7;
#pragma unroll
  for (int i = 0; i < 4; ++i) {
    int u = i * 256 + t, row = u >> 3, cb = (u & 7) << 4, ci0 = cb >> 1;
    f16x8 v;
    if (BR2 && ci0 < 16) v = *(const f16x8*)(y1 + (size_t)(px0 + row) * 16 + ci0);
    else                 v = *(const f16x8*)(xn + (size_t)(px0 + row) * 64 + ci0);
    *(f16x8*)((char*)As + row * 128 + (cb ^ ((row & 7) << 4))) = v;
  }
#pragma unroll
  for (int i = 0; i < 4; ++i) {
    int u = i * 256 + t, row = u >> 3, cb = (u & 7) << 4;
    f16x8 v = *(const f16x8*)(Wh + (size_t)(ceB + row) * 64 + (cb >> 1));
    *(f16x8*)((char*)Bs + row * 128 + (cb ^ ((row & 7) << 4))) = v;
  }
  __syncthreads();
  int l = t & 63, wv = t >> 6, lm = l & 15, kg = l >> 4;
  f32x4 acc[2][8];
#pragma unroll
  for (int a = 0; a < 2; ++a)
#pragma unroll
    for (int n = 0; n < 8; ++n) acc[a][n] = (f32x4){0.f, 0.f, 0.f, 0.f};
#pragma unroll
  for (int kk = 0; kk < 2; ++kk) {
    int kb = kk * 64 + kg * 16;
    f16x8 af[2];
#pragma unroll
    for (int mt = 0; mt < 2; ++mt) {
      int row = wv * 32 + mt * 16 + lm;
      af[mt] = *(const f16x8*)((char*)As + row * 128 + (kb ^ ((row & 7) << 4)));
    }
    f16x8 bf[8];
#pragma unroll
    for (int nt = 0; nt < 8; ++nt) {
      int row = nt * 16 + lm;
      bf[nt] = *(const f16x8*)((char*)Bs + row * 128 + (kb ^ ((row & 7) << 4)));
    }
#pragma unroll
    for (int mt = 0; mt < 2; ++mt)
#pragma unroll
      for (int nt = 0; nt < 8; ++nt)
        acc[mt][nt] = __builtin_amdgcn_mfma_f32_16x16x32_f16(af[mt], bf[nt], acc[mt][nt], 0, 0, 0);
  }
  float bz[8];
#pragma unroll
  for (int nt = 0; nt < 8; ++nt) bz[nt] = bias[ceB + nt * 16 + lm];
#pragma unroll
  for (int mt = 0; mt < 2; ++mt)
#pragma unroll
    for (int nt = 0; nt < 8; ++nt) {
      int ce = ceB + nt * 16 + lm;
      int pxb = px0 + wv * 32 + mt * 16 + kg * 4;
#pragma unroll
      for (int r = 0; r < 4; ++r) {
        float g = gelu_f(acc[mt][nt][r] + bz[nt]);
        e[(size_t)(pxb + r) * 256 + ce] = (f16)g;
      }
    }
}

// ---------------------------------------------------------------------------
// dw3x3+gelu (producer) + contract2 (K=256) + b4 -> u2[co][px].  8x16 tiles.
// Grid 512.  Per batch.
// ---------------------------------------------------------------------------
__global__ void __launch_bounds__(256) c2_kernel(
    const f16* __restrict__ e, const f16* __restrict__ W4h,
    const float* __restrict__ b4, const f16* __restrict__ w3pk,
    const f16* __restrict__ b3pk, f16* __restrict__ u2) {
  __shared__ __align__(16) f16 halo[184 * 64];    // [10x18 px][64 ce] swizzled
  __shared__ __align__(16) f16 As[8192];
  __shared__ __align__(16) f16 w3s[2304];
  __shared__ __align__(16) f16 b3s[256];
  int t = threadIdx.x, blk = blockIdx.x;
  int h0 = (blk >> 4) << 3, w0 = (blk & 15) << 4;
  for (int i = t; i < 288; i += 256)
    *(f16x8*)(w3s + i * 8) = *(const f16x8*)(w3pk + i * 8);
  if (t < 32) *(f16x8*)(b3s + t * 8) = *(const f16x8*)(b3pk + t * 8);
  int l = t & 63, wv = t >> 6, lm = l & 15, kg = l >> 4;
  int pxl = t & 127, chh = t >> 7, rl = pxl >> 4, cl = pxl & 15;
  f32x4 acc[2][4];
#pragma unroll
  for (int a = 0; a < 2; ++a)
#pragma unroll
    for (int n = 0; n < 4; ++n) acc[a][n] = (f32x4){0.f, 0.f, 0.f, 0.f};
  for (int kc = 0; kc < 4; ++kc) {
    if (kc) __syncthreads();
    for (int i = 0; i < 6; ++i) {
      int u = i * 256 + t;
      if (u < 1440) {
        int hp = u >> 3, cb = (u & 7) << 4;
        int hr = hp / 18, hc = hp - hr * 18;
        int h = h0 - 1 + hr, w = w0 - 1 + hc;
        f16x8 v = {0, 0, 0, 0, 0, 0, 0, 0};
        if ((unsigned)h < 256u && (unsigned)w < 256u)
          v = *(const f16x8*)(e + ((((size_t)h << 8)) + w) * 256 + kc * 64 + (cb >> 1));
        *(f16x8*)((char*)halo + hp * 128 + (cb ^ ((hp & 7) << 4))) = v;
      }
    }
    __syncthreads();
#pragma unroll
    for (int c8 = 0; c8 < 4; ++c8) {
      int ceL = chh * 32 + c8 * 8;
      int ceG = kc * 64 + ceL, g = ceG >> 3;
      f16x8 a8 = *(const f16x8*)(b3s + ceG);
#pragma unroll
      for (int ty = 0; ty < 3; ++ty)
#pragma unroll
        for (int tx = 0; tx < 3; ++tx) {
          int hp = (rl + ty) * 18 + (cl + tx);
          f16x8 xv = *(const f16x8*)((char*)halo + hp * 128 + ((ceL * 2) ^ ((hp & 7) << 4)));
          f16x8 wv8 = *(const f16x8*)(w3s + g * 72 + (ty * 3 + tx) * 8);
          a8 += xv * wv8;
        }
      f16x8 r8;
#pragma unroll
      for (int j2 = 0; j2 < 8; ++j2) r8[j2] = (f16)gelu_f((float)a8[j2]);
      *(f16x8*)((char*)As + pxl * 128 + ((ceL * 2) ^ ((pxl & 7) << 4))) = r8;
    }
    __syncthreads();
#pragma unroll
    for (int kk = 0; kk < 2; ++kk) {
      int kb = kk * 64 + kg * 16;
      f16x8 af[2];
#pragma unroll
      for (int mt = 0; mt < 2; ++mt) {
        int row = wv * 32 + mt * 16 + lm;
        af[mt] = *(const f16x8*)((char*)As + row * 128 + (kb ^ ((row & 7) << 4)));
      }
      f16x8 bf[4];
#pragma unroll
      for (int nt = 0; nt < 4; ++nt) {
        int co = nt * 16 + lm;
        bf[nt] = *(const f16x8*)(W4h + (size_t)co * 256 + kc * 64 + kk * 32 + kg * 8);
      }
#pragma unroll
      for (int mt = 0; mt < 2; ++mt)
#pragma unroll
        for (int nt = 0; nt < 4; ++nt)
          acc[mt][nt] = __builtin_amdgcn_mfma_f32_16x16x32_f16(af[mt], bf[nt], acc[mt][nt], 0, 0, 0);
    }
  }
  __syncthreads();
#pragma unroll
  for (int mt = 0; mt < 2; ++mt)
#pragma unroll
    for (int nt = 0; nt < 4; ++nt) {
      int c = nt * 16 + lm;
      float bz = b4[c];
#pragma unroll
      for (int r = 0; r < 4; ++r) {
        int m = wv * 32 + mt * 16 + kg * 4 + r;
        *(f16*)((char*)As + m * 128 + ((c * 2) ^ ((m & 7) << 4))) =
            (f16)(acc[mt][nt][r] + bz);
      }
    }
  __syncthreads();
  int co = t >> 2, q = t & 3;
  f16x8 o[4];
#pragma unroll
  for (int i = 0; i < 32; ++i) {
    int m = q * 32 + i;
    o[i >> 3][i & 7] =
        *(const f16*)((char*)As + m * 128 + ((co * 2) ^ ((m & 7) << 4)));
  }
  f16* up = u2 + ((size_t)co << 16) + (size_t)(h0 + 2 * q) * 256 + w0;
  *(f16x8*)(up) = o[0];
  *(f16x8*)(up + 8) = o[1];
  *(f16x8*)(up + 256) = o[2];
  *(f16x8*)(up + 256 + 8) = o[3];
}

// ---------------------------------------------------------------------------
// out = circconv8x8(u1,k1) + circconv8x8(u2,k2).  Wave = one c; lane = px in
// window; kp[64] packed (k1,k2) f16 pairs in VGPRs (staged via LDS);
// 32 windows/wave via readlane + fdot2.  Grid 512 = C * 8 parts.  Per batch.
// ---------------------------------------------------------------------------
__global__ void __launch_bounds__(256) fftmix_kernel(
    const f16* __restrict__ u1, const f16* __restrict__ u2,
    const float* __restrict__ kap1, const float* __restrict__ kap2,
    float* __restrict__ out, int b) {
  int blk = blockIdx.x;           // 0..511
  int c = blk >> 3, part = blk & 7;
  int t = threadIdx.x;
  int l = t & 63, wv = (t >> 6) & 3;
  int s = l >> 3, tq = l & 7;
  __shared__ unsigned int kls[64];
  if (t < 64) {
    f16 k1 = (f16)kap1[(c << 6) + t];
    f16 k2 = (f16)kap2[(c << 6) + t];
    kls[t] = (unsigned int)__builtin_bit_cast(unsigned short, k1) |
             ((unsigned int)__builtin_bit_cast(unsigned short, k2) << 16);
  }
  __syncthreads();
  unsigned int kp[64];
#pragma unroll
  for (int j = 0; j < 64; ++j) {
    int idx = (((s - (j >> 3)) & 7) << 3) | ((tq - (j & 7)) & 7);
    kp[j] = kls[idx];
  }
  size_t cb = ((size_t)c) << 16;
  size_t obase = ((size_t)(b * 64 + c)) << 16;
  int win0 = part * 128 + wv * 32;
  for (int it = 0; it < 32; ++it) {
    int win = win0 + it;
    int wh = win >> 5, ww = win & 31;
    size_t pix = (size_t)((wh * 8 + s) << 8) + ww * 8 + tq;
    unsigned int pk =
        (unsigned int)__builtin_bit_cast(unsigned short, u1[cb + pix]) |
        ((unsigned int)__builtin_bit_cast(unsigned short, u2[cb + pix]) << 16);
    float acc = 0.f;
#pragma unroll
    for (int j = 0; j < 64; ++j) {
      unsigned int bc = (unsigned int)__builtin_amdgcn_readlane((int)pk, j);
      acc = dot2f(__builtin_bit_cast(f16x2, bc),
                  __builtin_bit_cast(f16x2, kp[j]), acc);
    }
    out[obase + pix] = acc;
  }
}

// ---------------------------------------------------------------------------
__global__ void diag_kernel(float* __restrict__ out, float code, int n) {
  int i = blockIdx.x * 256 + threadIdx.x;
  for (int p = i; p < n; p += 256 * 4096) out[p] = (p == 0) ? code : 0.f;
}

// ---------------------------------------------------------------------------
extern "C" void kernel_launch(void* const* d_in, const int* in_sizes, int n_in,
                              void* d_out, int out_size, void* d_ws,
                              size_t ws_size, hipStream_t stream) {
  const float* x       = (const float*)d_in[0];
  const float* ln_w    = (const float*)d_in[1];
  const float* ln_b    = (const float*)d_in[2];
  const float* pconv_w = (const float*)d_in[3];
  const float* pconv_b = (const float*)d_in[4];
  const float* w0      = (const float*)d_in[5];
  const float* b0      = (const float*)d_in[6];
  const float* w1      = (const float*)d_in[7];
  const float* b1      = (const float*)d_in[8];
  const float* w2      = (const float*)d_in[9];
  const float* b2      = (const float*)d_in[10];
  const float* w3      = (const float*)d_in[11];
  const float* b3      = (const float*)d_in[12];
  const float* w4      = (const float*)d_in[13];
  const float* b4      = (const float*)d_in[14];
  const float* fftw1   = (const float*)d_in[15];
  const float* fftw2   = (const float*)d_in[16];

  const size_t OFF_KAP1 = 0;                        // f32 [64][64] = 16 KB
  const size_t OFF_KAP2 = 16384;
  const size_t OFF_W0H  = 32768;                    // 32 KB each
  const size_t OFF_W1H  = 65536;
  const size_t OFF_W2H  = 98304;
  const size_t OFF_W4H  = 131072;
  const size_t OFF_W3PK = 163840;                   // 4608 B
  const size_t OFF_B3PK = 168448;                   // 512 B
  const size_t OFF_XN   = 168960;                   // f16 [65536][64] = 8 MB; u2 overlays
  const size_t OFF_Y1   = OFF_XN + 8388608ull;      // f16 [65536][16] = 2 MB
  const size_t OFF_E    = OFF_Y1 + 2097152ull;      // f16 [65536][256] = 32 MB
  const size_t OFF_U1   = OFF_E + 33554432ull;      // f16 [64][65536] = 8 MB
  const size_t WS_NEED  = OFF_U1 + 8388608ull;      // 52,597,760 B (proven fits)

  float* outF = (float*)d_out;
  if (ws_size < WS_NEED) {
    diag_kernel<<<4096, 256, 0, stream>>>(outF, 1000.0f + (float)(ws_size >> 20), 16777216);
    return;
  }
  char* ws = (char*)d_ws;
  float* kap1 = (float*)(ws + OFF_KAP1);
  float* kap2 = (float*)(ws + OFF_KAP2);
  f16* W0h  = (f16*)(ws + OFF_W0H);
  f16* W1h  = (f16*)(ws + OFF_W1H);
  f16* W2h  = (f16*)(ws + OFF_W2H);
  f16* W4h  = (f16*)(ws + OFF_W4H);
  f16* w3pk = (f16*)(ws + OFF_W3PK);
  f16* b3pk = (f16*)(ws + OFF_B3PK);
  f16* XN   = (f16*)(ws + OFF_XN);
  f16* U2   = (f16*)(ws + OFF_XN);   // overlays XN (xn dead after exp1)
  f16* Y1   = (f16*)(ws + OFF_Y1);
  f16* E    = (f16*)(ws + OFF_E);
  f16* U1   = (f16*)(ws + OFF_U1);

  build_kappa_kernel<<<128, 64, 0, stream>>>(fftw1, fftw2, kap1, kap2);
  preconv_kernel<<<266, 256, 0, stream>>>(w0, w1, w2, w4, w3, b3,
                                          W0h, W1h, W2h, W4h, w3pk, b3pk);
  for (int b = 0; b < 4; ++b) {
    ln_kernel<<<256, 256, 0, stream>>>(x, ln_w, ln_b, XN, b);
    pconv_kernel<<<256, 256, 0, stream>>>(XN, pconv_w, pconv_b, Y1);
    b1_kernel<<<512, 256, 0, stream>>>(XN, W0h, b0, W2h, b2, U1);
    expand_kernel<1><<<1024, 256, 0, stream>>>(XN, Y1, W1h, b1, E);
    c2_kernel<<<512, 256, 0, stream>>>(E, W4h, b4, w3pk, b3pk, U2);
    fftmix_kernel<<<512, 256, 0, stream>>>(U1, U2, kap1, kap2, outF, b);
  }
}

// Round 7
// 408.301 us; speedup vs baseline: 4.5459x; 1.2007x over previous
//
#include <hip/hip_runtime.h>

// Problem: B=4, C=64, H=W=256, D=16, C4=256, P=8.  HW=65536.
// xn (NHWC f16, 32MB) lives in d_out[0:32MB); u1 planes b=0..2 live in
// d_out[32MB + 8MB*b); u1(3), y1, u2 live in ws.  fftmix launched per batch
// in order b=0..3 so out(b) only overwrites consumed regions.

typedef _Float16 f16;
typedef _Float16 f16x2 __attribute__((ext_vector_type(2)));
typedef _Float16 f16x8 __attribute__((ext_vector_type(8)));
typedef float f32x4 __attribute__((ext_vector_type(4)));

__device__ __forceinline__ float gelu_f(float x) {
  float u = 1.5957691216f * (x + 0.044715f * x * x * x);
  float t = exp2f(-1.4426950409f * u);
#if __has_builtin(__builtin_amdgcn_rcpf)
  return x * __builtin_amdgcn_rcpf(1.0f + t);
#else
  return x / (1.0f + t);
#endif
}

__device__ __forceinline__ float dot2f(f16x2 a, f16x2 b, float c) {
#if __has_builtin(__builtin_amdgcn_fdot2)
  return __builtin_amdgcn_fdot2(a, b, c, false);
#else
  return c + (float)a.x * (float)b.x + (float)a.y * (float)b.y;
#endif
}

// ---------------------------------------------------------------------------
__global__ void build_kappa_kernel(const float* __restrict__ fw1,
                                   const float* __restrict__ fw2,
                                   float* __restrict__ kap1,
                                   float* __restrict__ kap2) {
  int which = blockIdx.x >> 6, c = blockIdx.x & 63;
  const float* fw = which ? fw2 : fw1;
  float* kap = which ? kap2 : kap1;
  int t = threadIdx.x, a = t >> 3, bb = t & 7;
  __shared__ float Wt[64];
  __shared__ float ct[8];
  if (t == 0) {
    const float r2 = 0.70710678118654752440f;
    ct[0] = 1.f; ct[1] = r2; ct[2] = 0.f; ct[3] = -r2;
    ct[4] = -1.f; ct[5] = -r2; ct[6] = 0.f; ct[7] = r2;
  }
  {
    int u = a, v = bb;
    Wt[t] = (v <= 4) ? fw[c * 40 + u * 5 + v]
                     : fw[c * 40 + ((8 - u) & 7) * 5 + (8 - v)];
  }
  __syncthreads();
  float acc = 0.f;
  for (int u = 0; u < 8; ++u)
    for (int v = 0; v < 8; ++v)
      acc += Wt[u * 8 + v] * ct[(u * a + v * bb) & 7];
  kap[c * 64 + t] = acc * 0.015625f;
}

// ---------------------------------------------------------------------------
__global__ void preconv_kernel(const float* __restrict__ w0, const float* __restrict__ w1,
                               const float* __restrict__ w2, const float* __restrict__ w4,
                               const float* __restrict__ w3, const float* __restrict__ b3,
                               f16* __restrict__ W0h, f16* __restrict__ W1h,
                               f16* __restrict__ W2h, f16* __restrict__ W4h,
                               f16* __restrict__ w3pk, f16* __restrict__ b3pk) {
  int i = blockIdx.x * 256 + threadIdx.x;
  if (i < 16384) W0h[i] = (f16)w0[i];
  else if (i < 32768) W1h[i - 16384] = (f16)w1[i - 16384];
  else if (i < 49152) W2h[i - 32768] = (f16)w2[i - 32768];
  else if (i < 65536) W4h[i - 49152] = (f16)w4[i - 49152];
  else if (i < 67840) {
    int j = i - 65536;                 // [g][tap][k]: value = w3[(g*8+k)*9+tap]
    int g = j / 72, r = j % 72, tap = r >> 3, k = r & 7;
    w3pk[j] = (f16)w3[(g * 8 + k) * 9 + tap];
  } else if (i < 68096) {
    int k = i - 67840;
    b3pk[k] = (f16)b3[k];
  }
}

// ---------------------------------------------------------------------------
// LayerNorm.  x NCHW f32 -> xn NHWC f16.  grid (256, 4).
// ---------------------------------------------------------------------------
__global__ void __launch_bounds__(256) ln_kernel(const float* __restrict__ x,
                                                 const float* __restrict__ lnw,
                                                 const float* __restrict__ lnb,
                                                 f16* __restrict__ xn) {
  int b = blockIdx.y;
  int px = blockIdx.x * 256 + threadIdx.x;
  const float* xp = x + ((size_t)b << 22) + px;
  float v[64];
  float s = 0.f;
#pragma unroll
  for (int c = 0; c < 64; ++c) { v[c] = xp[(size_t)c << 16]; s += v[c]; }
  float mu = s * (1.f / 64.f), s2 = 0.f;
#pragma unroll
  for (int c = 0; c < 64; ++c) { float d = v[c] - mu; s2 += d * d; }
  float rstd = rsqrtf(s2 * (1.f / 64.f) + 1e-6f);
  f16* op = xn + (size_t)b * 4194304 + (size_t)px * 64;
#pragma unroll
  for (int g = 0; g < 8; ++g) {
    f16x8 pk;
#pragma unroll
    for (int j = 0; j < 8; ++j) {
      int c = g * 8 + j;
      pk[j] = (f16)((v[c] - mu) * rstd * lnw[c] + lnb[c]);
    }
    *(f16x8*)(op + g * 8) = pk;
  }
}

// ---------------------------------------------------------------------------
// 3x3 dense conv 16ci->16co on xn c<16 -> y1 NHWC f16.  grid (256, 4).
// ---------------------------------------------------------------------------
__global__ void __launch_bounds__(256) pconv_kernel(const f16* __restrict__ xn,
                                                    const float* __restrict__ pw,
                                                    const float* __restrict__ pb,
                                                    f16* __restrict__ y1) {
  __shared__ __align__(16) char halo[18 * 640];
  __shared__ f16 wpk[2304];                      // [co][tap][ci]
  __shared__ float pbs[16];
  int t = threadIdx.x, blk = blockIdx.x, b = blockIdx.y;
  const f16* xnb = xn + (size_t)b * 4194304;
  f16* y1b = y1 + (size_t)b * 1048576;
  int h0 = (blk >> 4) << 4, w0 = (blk & 15) << 4;
  for (int i = t; i < 2304; i += 256) {
    int co = i / 144, r = i % 144, tap = r >> 4, ci = r & 15;
    wpk[i] = (f16)pw[co * 144 + ci * 9 + tap];
  }
  if (t < 16) pbs[t] = pb[t];
  for (int i = 0; i < 3; ++i) {
    int u = i * 256 + t;
    if (u < 648) {
      int hp = u >> 1, half = u & 1;
      int hr = hp / 18, hc = hp - hr * 18;
      int h = h0 - 1 + hr, w = w0 - 1 + hc;
      f16x8 v = {0, 0, 0, 0, 0, 0, 0, 0};
      if ((unsigned)h < 256u && (unsigned)w < 256u)
        v = *(const f16x8*)(xnb + ((((size_t)h << 8)) + w) * 64 + half * 8);
      *(f16x8*)(halo + hr * 640 + ((hc * 32 + half * 16) ^ ((hr & 7) << 4))) = v;
    }
  }
  __syncthreads();
  int rl = t >> 4, cl = t & 15;
  float acc[16];
#pragma unroll
  for (int co = 0; co < 16; ++co) acc[co] = pbs[co];
#pragma unroll
  for (int ty = 0; ty < 3; ++ty)
#pragma unroll
    for (int tx = 0; tx < 3; ++tx) {
      int hr = rl + ty, hc = cl + tx, tap = ty * 3 + tx;
      f16x8 ld0 = *(const f16x8*)(halo + hr * 640 + ((hc * 32) ^ ((hr & 7) << 4)));
      f16x8 ld1 = *(const f16x8*)(halo + hr * 640 + ((hc * 32 + 16) ^ ((hr & 7) << 4)));
#pragma unroll
      for (int co = 0; co < 16; ++co) {
#pragma unroll
        for (int p = 0; p < 4; ++p) {
          f16x2 xp = {ld0[2 * p], ld0[2 * p + 1]};
          f16x2 wp = *(const f16x2*)&wpk[co * 144 + tap * 16 + 2 * p];
          acc[co] = dot2f(xp, wp, acc[co]);
        }
#pragma unroll
        for (int p = 0; p < 4; ++p) {
          f16x2 xp = {ld1[2 * p], ld1[2 * p + 1]};
          f16x2 wp = *(const f16x2*)&wpk[co * 144 + tap * 16 + 8 + 2 * p];
          acc[co] = dot2f(xp, wp, acc[co]);
        }
      }
    }
  size_t px = (((size_t)(h0 + rl)) << 8) + w0 + cl;
  f16x8 o0, o1;
#pragma unroll
  for (int j = 0; j < 8; ++j) { o0[j] = (f16)acc[j]; o1[j] = (f16)acc[8 + j]; }
  *(f16x8*)(y1b + px * 16) = o0;
  *(f16x8*)(y1b + px * 16 + 8) = o1;
}

// ---------------------------------------------------------------------------
// Fused branch 1: u1[co][px] = (gelu(xn.W0+b0)).W2 + b2, 128-px strips.
// grid (512, 4).  u1 plane: b<3 -> d_out overlay, b=3 -> ws.
// ---------------------------------------------------------------------------
__global__ void __launch_bounds__(256) b1_kernel(
    const f16* __restrict__ xn, const f16* __restrict__ W0h,
    const float* __restrict__ b0, const f16* __restrict__ W2h,
    const float* __restrict__ b2, f16* __restrict__ u1d,
    f16* __restrict__ u1w) {
  __shared__ __align__(16) f16 As[8192];   // xn strip [128 px][64 ci] swizzled
  __shared__ __align__(16) f16 Es[8192];   // e chunk [128 px][64 ce] swizzled
  int t = threadIdx.x, b = blockIdx.y;
  const f16* xnb = xn + (size_t)b * 4194304;
  f16* u1b = (b < 3) ? (u1d + (size_t)b * 4194304) : u1w;
  int px0 = blockIdx.x << 7;
#pragma unroll
  for (int i = 0; i < 4; ++i) {
    int u = i * 256 + t, row = u >> 3, cb = (u & 7) << 4;
    f16x8 v = *(const f16x8*)(xnb + (size_t)(px0 + row) * 64 + (cb >> 1));
    *(f16x8*)((char*)As + row * 128 + (cb ^ ((row & 7) << 4))) = v;
  }
  __syncthreads();
  int l = t & 63, wv = t >> 6, lm = l & 15, kg = l >> 4;
  f32x4 uacc[2][4];
#pragma unroll
  for (int a = 0; a < 2; ++a)
#pragma unroll
    for (int n = 0; n < 4; ++n) uacc[a][n] = (f32x4){0.f, 0.f, 0.f, 0.f};
  for (int cc = 0; cc < 4; ++cc) {
    f32x4 eacc[2][4];
#pragma unroll
    for (int a = 0; a < 2; ++a)
#pragma unroll
      for (int n = 0; n < 4; ++n) eacc[a][n] = (f32x4){0.f, 0.f, 0.f, 0.f};
#pragma unroll
    for (int kk = 0; kk < 2; ++kk) {
      int kb = kk * 64 + kg * 16;
      f16x8 af[2];
#pragma unroll
      for (int mt = 0; mt < 2; ++mt) {
        int row = wv * 32 + mt * 16 + lm;
        af[mt] = *(const f16x8*)((char*)As + row * 128 + (kb ^ ((row & 7) << 4)));
      }
      f16x8 bf[4];
#pragma unroll
      for (int nt = 0; nt < 4; ++nt) {
        int co = cc * 64 + nt * 16 + lm;
        bf[nt] = *(const f16x8*)(W0h + (size_t)co * 64 + kk * 32 + kg * 8);
      }
#pragma unroll
      for (int mt = 0; mt < 2; ++mt)
#pragma unroll
        for (int nt = 0; nt < 4; ++nt)
          eacc[mt][nt] = __builtin_amdgcn_mfma_f32_16x16x32_f16(af[mt], bf[nt], eacc[mt][nt], 0, 0, 0);
    }
    if (cc) __syncthreads();
#pragma unroll
    for (int mt = 0; mt < 2; ++mt)
#pragma unroll
      for (int nt = 0; nt < 4; ++nt) {
        int c = nt * 16 + lm;
        float bz = b0[cc * 64 + c];
#pragma unroll
        for (int r = 0; r < 4; ++r) {
          int m = wv * 32 + mt * 16 + kg * 4 + r;
          *(f16*)((char*)Es + m * 128 + ((c * 2) ^ ((m & 7) << 4))) =
              (f16)gelu_f(eacc[mt][nt][r] + bz);
        }
      }
    __syncthreads();
#pragma unroll
    for (int kk = 0; kk < 2; ++kk) {
      int kb = kk * 64 + kg * 16;
      f16x8 af[2];
#pragma unroll
      for (int mt = 0; mt < 2; ++mt) {
        int row = wv * 32 + mt * 16 + lm;
        af[mt] = *(const f16x8*)((char*)Es + row * 128 + (kb ^ ((row & 7) << 4)));
      }
      f16x8 bf[4];
#pragma unroll
      for (int nt = 0; nt < 4; ++nt) {
        int co = nt * 16 + lm;
        bf[nt] = *(const f16x8*)(W2h + (size_t)co * 256 + cc * 64 + kk * 32 + kg * 8);
      }
#pragma unroll
      for (int mt = 0; mt < 2; ++mt)
#pragma unroll
        for (int nt = 0; nt < 4; ++nt)
          uacc[mt][nt] = __builtin_amdgcn_mfma_f32_16x16x32_f16(af[mt], bf[nt], uacc[mt][nt], 0, 0, 0);
    }
    __syncthreads();
  }
#pragma unroll
  for (int mt = 0; mt < 2; ++mt)
#pragma unroll
    for (int nt = 0; nt < 4; ++nt) {
      int c = nt * 16 + lm;
      float bz = b2[c];
#pragma unroll
      for (int r = 0; r < 4; ++r) {
        int m = wv * 32 + mt * 16 + kg * 4 + r;
        *(f16*)((char*)Es + m * 128 + ((c * 2) ^ ((m & 7) << 4))) =
            (f16)(uacc[mt][nt][r] + bz);
      }
    }
  __syncthreads();
  int co = t >> 2, q = t & 3;
  f16x8 o[4];
#pragma unroll
  for (int i = 0; i < 32; ++i) {
    int m = q * 32 + i;
    o[i >> 3][i & 7] =
        *(const f16*)((char*)Es + m * 128 + ((co * 2) ^ ((m & 7) << 4)));
  }
  f16* up = u1b + ((size_t)co << 16) + px0 + q * 32;
#pragma unroll
  for (int ss = 0; ss < 4; ++ss) *(f16x8*)(up + ss * 8) = o[ss];
}

// ---------------------------------------------------------------------------
// Fused branch 2: expand1(halo recompute) + dw3x3 + gelu + contract2 -> u2.
// 8x16 output tile, 10x18 halo (192 padded rows).  Per kc(4) x sub(2):
// expand 32 ce -> Es(LDS) -> dw+gelu -> As(LDS) -> contract K=32 partial.
// grid (512, 4).
// ---------------------------------------------------------------------------
__global__ void __launch_bounds__(256) b2_kernel(
    const f16* __restrict__ xn, const f16* __restrict__ y1,
    const f16* __restrict__ W1h, const float* __restrict__ b1v,
    const f16* __restrict__ W4h, const float* __restrict__ b4,
    const f16* __restrict__ w3pk, const f16* __restrict__ b3pk,
    f16* __restrict__ u2) {
  __shared__ __align__(16) f16 xin[12288];  // 192 rows x 64 ci, 128B rows, &7 swz
  __shared__ __align__(16) f16 Es[6144];    // 192 rows x 32 ce, 64B rows, &3 swz
  __shared__ __align__(16) f16 Gs[4096];    // 128 px x 32 ce, 64B rows, &3 swz
  __shared__ __align__(16) f16 w3s[2304];
  __shared__ __align__(16) f16 b3s[256];
  int t = threadIdx.x, blk = blockIdx.x, b = blockIdx.y;
  const f16* xnb = xn + (size_t)b * 4194304;
  const f16* y1b = y1 + (size_t)b * 1048576;
  f16* u2b = u2 + (size_t)b * 4194304;
  int h0 = (blk >> 4) << 3, w0 = (blk & 15) << 4;
  for (int i = t; i < 288; i += 256)
    *(f16x8*)(w3s + i * 8) = *(const f16x8*)(w3pk + i * 8);
  if (t < 32) *(f16x8*)(b3s + t * 8) = *(const f16x8*)(b3pk + t * 8);
  // stage xin: halo rows hp = hr*18+hc (hr 0..9, hc 0..17); rows 180..191 zero
#pragma unroll
  for (int i = 0; i < 6; ++i) {
    int u = i * 256 + t;                 // 0..1535 = 192 rows x 8 parts
    int hp = u >> 3, part = u & 7;
    f16x8 v = {0, 0, 0, 0, 0, 0, 0, 0};
    if (hp < 180) {
      int hr = hp / 18, hc = hp - hr * 18;
      int h = h0 - 1 + hr, w = w0 - 1 + hc;
      if ((unsigned)h < 256u && (unsigned)w < 256u) {
        size_t px = ((size_t)h << 8) + w;
        v = (part < 2) ? *(const f16x8*)(y1b + px * 16 + part * 8)
                       : *(const f16x8*)(xnb + px * 64 + part * 8);
      }
    }
    *(f16x8*)((char*)xin + hp * 128 + ((part * 16) ^ ((hp & 7) << 4))) = v;
  }
  __syncthreads();
  int l = t & 63, wv = t >> 6, lm = l & 15, kg = l >> 4;
  int pxl = t & 127, chh = t >> 7, rl = pxl >> 4, cl = pxl & 15;
  f32x4 uacc[2][4];
#pragma unroll
  for (int a = 0; a < 2; ++a)
#pragma unroll
    for (int n = 0; n < 4; ++n) uacc[a][n] = (f32x4){0.f, 0.f, 0.f, 0.f};
  for (int kc = 0; kc < 4; ++kc) {
#pragma unroll
    for (int sub = 0; sub < 2; ++sub) {
      int ce0 = kc * 64 + sub * 32;
      // --- expand: Es[192 rows][32 ce] (12 m-tiles: wave wv does wv,wv+4,wv+8)
      f32x4 eacc[3][2];
#pragma unroll
      for (int a = 0; a < 3; ++a)
#pragma unroll
        for (int n = 0; n < 2; ++n) eacc[a][n] = (f32x4){0.f, 0.f, 0.f, 0.f};
#pragma unroll
      for (int kk = 0; kk < 2; ++kk) {
        int kb = kk * 64 + kg * 16;
        f16x8 af[3];
#pragma unroll
        for (int mtl = 0; mtl < 3; ++mtl) {
          int row = (mtl * 4 + wv) * 16 + lm;
          af[mtl] = *(const f16x8*)((char*)xin + row * 128 + (kb ^ ((row & 7) << 4)));
        }
        f16x8 bf[2];
#pragma unroll
        for (int nt = 0; nt < 2; ++nt) {
          int ce = ce0 + nt * 16 + lm;
          bf[nt] = *(const f16x8*)(W1h + (size_t)ce * 64 + kk * 32 + kg * 8);
        }
#pragma unroll
        for (int mtl = 0; mtl < 3; ++mtl)
#pragma unroll
          for (int nt = 0; nt < 2; ++nt)
            eacc[mtl][nt] = __builtin_amdgcn_mfma_f32_16x16x32_f16(af[mtl], bf[nt], eacc[mtl][nt], 0, 0, 0);
      }
      float bz0 = b1v[ce0 + lm], bz1 = b1v[ce0 + 16 + lm];
#pragma unroll
      for (int mtl = 0; mtl < 3; ++mtl)
#pragma unroll
        for (int nt = 0; nt < 2; ++nt) {
          int ceL = nt * 16 + lm;
          float bz = nt ? bz1 : bz0;
#pragma unroll
          for (int r = 0; r < 4; ++r) {
            int row = (mtl * 4 + wv) * 16 + kg * 4 + r;
            *(f16*)((char*)Es + row * 64 + ((ceL * 2) ^ ((row & 3) << 4))) =
                (f16)gelu_f(eacc[mtl][nt][r] + bz);
          }
        }
      __syncthreads();
      // --- dw 3x3 + gelu -> Gs[128 px][32 ce]
#pragma unroll
      for (int c8 = 0; c8 < 2; ++c8) {
        int ceL = chh * 16 + c8 * 8;
        int ceG = ce0 + ceL, g9 = ceG >> 3;
        f16x8 a8 = *(const f16x8*)(b3s + ceG);
#pragma unroll
        for (int ty = 0; ty < 3; ++ty)
#pragma unroll
          for (int tx = 0; tx < 3; ++tx) {
            int hp = (rl + ty) * 18 + (cl + tx);
            f16x8 xv = *(const f16x8*)((char*)Es + hp * 64 + ((ceL * 2) ^ ((hp & 3) << 4)));
            f16x8 wv8 = *(const f16x8*)(w3s + g9 * 72 + (ty * 3 + tx) * 8);
            a8 += xv * wv8;
          }
        f16x8 r8;
#pragma unroll
        for (int j2 = 0; j2 < 8; ++j2) r8[j2] = (f16)gelu_f((float)a8[j2]);
        *(f16x8*)((char*)Gs + pxl * 64 + ((ceL * 2) ^ ((pxl & 3) << 4))) = r8;
      }
      __syncthreads();
      // --- contract partial (K=32)
      f16x8 af2[2];
#pragma unroll
      for (int mt = 0; mt < 2; ++mt) {
        int row = wv * 32 + mt * 16 + lm;
        af2[mt] = *(const f16x8*)((char*)Gs + row * 64 + ((kg * 16) ^ ((row & 3) << 4)));
      }
      f16x8 bf2[4];
#pragma unroll
      for (int nt = 0; nt < 4; ++nt) {
        int co = nt * 16 + lm;
        bf2[nt] = *(const f16x8*)(W4h + (size_t)co * 256 + ce0 + kg * 8);
      }
#pragma unroll
      for (int mt = 0; mt < 2; ++mt)
#pragma unroll
        for (int nt = 0; nt < 4; ++nt)
          uacc[mt][nt] = __builtin_amdgcn_mfma_f32_16x16x32_f16(af2[mt], bf2[nt], uacc[mt][nt], 0, 0, 0);
      __syncthreads();
    }
  }
  // --- epilogue: uacc + b4 -> xin (dead) -> coalesced u2 write
#pragma unroll
  for (int mt = 0; mt < 2; ++mt)
#pragma unroll
    for (int nt = 0; nt < 4; ++nt) {
      int c = nt * 16 + lm;
      float bz = b4[c];
#pragma unroll
      for (int r = 0; r < 4; ++r) {
        int m = wv * 32 + mt * 16 + kg * 4 + r;
        *(f16*)((char*)xin + m * 128 + ((c * 2) ^ ((m & 7) << 4))) =
            (f16)(uacc[mt][nt][r] + bz);
      }
    }
  __syncthreads();
  int co = t >> 2, q = t & 3;
  f16x8 o[4];
#pragma unroll
  for (int i = 0; i < 32; ++i) {
    int m = q * 32 + i;
    o[i >> 3][i & 7] =
        *(const f16*)((char*)xin + m * 128 + ((co * 2) ^ ((m & 7) << 4)));
  }
  f16* up = u2b + ((size_t)co << 16) + (size_t)(h0 + 2 * q) * 256 + w0;
  *(f16x8*)(up) = o[0];
  *(f16x8*)(up + 8) = o[1];
  *(f16x8*)(up + 256) = o[2];
  *(f16x8*)(up + 256 + 8) = o[3];
}

// ---------------------------------------------------------------------------
// out(b) = circconv8x8(u1,k1) + circconv8x8(u2,k2).  Per batch, grid 512.
// ---------------------------------------------------------------------------
__global__ void __launch_bounds__(256) fftmix_kernel(
    const f16* __restrict__ u1, const f16* __restrict__ u2,
    const float* __restrict__ kap1, const float* __restrict__ kap2,
    float* __restrict__ out, int b) {
  int blk = blockIdx.x;
  int c = blk >> 3, part = blk & 7;
  int t = threadIdx.x;
  int l = t & 63, wv = (t >> 6) & 3;
  int s = l >> 3, tq = l & 7;
  __shared__ unsigned int kls[64];
  if (t < 64) {
    f16 k1 = (f16)kap1[(c << 6) + t];
    f16 k2 = (f16)kap2[(c << 6) + t];
    kls[t] = (unsigned int)__builtin_bit_cast(unsigned short, k1) |
             ((unsigned int)__builtin_bit_cast(unsigned short, k2) << 16);
  }
  __syncthreads();
  unsigned int kp[64];
#pragma unroll
  for (int j = 0; j < 64; ++j) {
    int idx = (((s - (j >> 3)) & 7) << 3) | ((tq - (j & 7)) & 7);
    kp[j] = kls[idx];
  }
  size_t cb = ((size_t)c) << 16;
  size_t obase = ((size_t)(b * 64 + c)) << 16;
  int win0 = part * 128 + wv * 32;
  for (int it = 0; it < 32; ++it) {
    int win = win0 + it;
    int wh = win >> 5, ww = win & 31;
    size_t pix = (size_t)((wh * 8 + s) << 8) + ww * 8 + tq;
    unsigned int pk =
        (unsigned int)__builtin_bit_cast(unsigned short, u1[cb + pix]) |
        ((unsigned int)__builtin_bit_cast(unsigned short, u2[cb + pix]) << 16);
    float acc = 0.f;
#pragma unroll
    for (int j = 0; j < 64; ++j) {
      unsigned int bc = (unsigned int)__builtin_amdgcn_readlane((int)pk, j);
      acc = dot2f(__builtin_bit_cast(f16x2, bc),
                  __builtin_bit_cast(f16x2, kp[j]), acc);
    }
    out[obase + pix] = acc;
  }
}

// ---------------------------------------------------------------------------
__global__ void diag_kernel(float* __restrict__ out, float code, int n) {
  int i = blockIdx.x * 256 + threadIdx.x;
  for (int p = i; p < n; p += 256 * 4096) out[p] = (p == 0) ? code : 0.f;
}

// ---------------------------------------------------------------------------
extern "C" void kernel_launch(void* const* d_in, const int* in_sizes, int n_in,
                              void* d_out, int out_size, void* d_ws,
                              size_t ws_size, hipStream_t stream) {
  const float* x       = (const float*)d_in[0];
  const float* ln_w    = (const float*)d_in[1];
  const float* ln_b    = (const float*)d_in[2];
  const float* pconv_w = (const float*)d_in[3];
  const float* pconv_b = (const float*)d_in[4];
  const float* w0      = (const float*)d_in[5];
  const float* b0      = (const float*)d_in[6];
  const float* w1      = (const float*)d_in[7];
  const float* b1      = (const float*)d_in[8];
  const float* w2      = (const float*)d_in[9];
  const float* b2      = (const float*)d_in[10];
  const float* w3      = (const float*)d_in[11];
  const float* b3      = (const float*)d_in[12];
  const float* w4      = (const float*)d_in[13];
  const float* b4      = (const float*)d_in[14];
  const float* fftw1   = (const float*)d_in[15];
  const float* fftw2   = (const float*)d_in[16];

  const size_t OFF_KAP1 = 0;                        // f32 [64][64] = 16 KB
  const size_t OFF_KAP2 = 16384;
  const size_t OFF_W0H  = 32768;                    // 32 KB each
  const size_t OFF_W1H  = 65536;
  const size_t OFF_W2H  = 98304;
  const size_t OFF_W4H  = 131072;
  const size_t OFF_W3PK = 163840;                   // 4608 B
  const size_t OFF_B3PK = 168448;                   // 512 B
  const size_t OFF_Y1   = 168960;                   // f16 4 x [65536][16] = 8 MB
  const size_t OFF_U2   = OFF_Y1 + 8388608ull;      // f16 4 x [64][65536] = 32 MB
  const size_t OFF_U13  = OFF_U2 + 33554432ull;     // f16 [64][65536] = 8 MB (b=3)
  const size_t WS_NEED  = OFF_U13 + 8388608ull;     // 50,500,608 B (< proven 58.75 MB)

  float* outF = (float*)d_out;
  if (ws_size < WS_NEED) {
    diag_kernel<<<4096, 256, 0, stream>>>(outF, 1000.0f + (float)(ws_size >> 20), 16777216);
    return;
  }
  char* ws = (char*)d_ws;
  float* kap1 = (float*)(ws + OFF_KAP1);
  float* kap2 = (float*)(ws + OFF_KAP2);
  f16* W0h  = (f16*)(ws + OFF_W0H);
  f16* W1h  = (f16*)(ws + OFF_W1H);
  f16* W2h  = (f16*)(ws + OFF_W2H);
  f16* W4h  = (f16*)(ws + OFF_W4H);
  f16* w3pk = (f16*)(ws + OFF_W3PK);
  f16* b3pk = (f16*)(ws + OFF_B3PK);
  f16* Y1   = (f16*)(ws + OFF_Y1);
  f16* U2   = (f16*)(ws + OFF_U2);
  f16* U13  = (f16*)(ws + OFF_U13);

  // d_out overlay: xn = f16[0:32MB); u1(b<3) = f16[32MB + 8MB*b)
  f16* XN  = (f16*)d_out;
  f16* U1D = (f16*)d_out + 16777216;

  build_kappa_kernel<<<128, 64, 0, stream>>>(fftw1, fftw2, kap1, kap2);
  preconv_kernel<<<266, 256, 0, stream>>>(w0, w1, w2, w4, w3, b3,
                                          W0h, W1h, W2h, W4h, w3pk, b3pk);
  ln_kernel<<<dim3(256, 4), 256, 0, stream>>>(x, ln_w, ln_b, XN);
  pconv_kernel<<<dim3(256, 4), 256, 0, stream>>>(XN, pconv_w, pconv_b, Y1);
  b1_kernel<<<dim3(512, 4), 256, 0, stream>>>(XN, W0h, b0, W2h, b2, U1D, U13);
  b2_kernel<<<dim3(512, 4), 256, 0, stream>>>(XN, Y1, W1h, b1, W4h, b4,
                                              w3pk, b3pk, U2);
  for (int b = 0; b < 4; ++b) {
    const f16* u1b = (b < 3) ? (U1D + (size_t)b * 4194304) : U13;
    fftmix_kernel<<<512, 256, 0, stream>>>(u1b, U2 + (size_t)b * 4194304,
                                           kap1, kap2, outF, b);
  }
}

// Round 8
// 400.649 us; speedup vs baseline: 4.6328x; 1.0191x over previous
//
#include <hip/hip_runtime.h>

// Problem: B=4, C=64, H=W=256, D=16, C4=256, P=8.  HW=65536.
// xn (NHWC f16, 32MB) lives in d_out[0:32MB); u1 planes b=0..2 live in
// d_out[32MB + 8MB*b); u1(3), y1, u2 live in ws.  fftmix launched per batch
// in order b=0..3 so out(b) only overwrites consumed regions.

typedef _Float16 f16;
typedef _Float16 f16x2 __attribute__((ext_vector_type(2)));
typedef _Float16 f16x8 __attribute__((ext_vector_type(8)));
typedef float f32x4 __attribute__((ext_vector_type(4)));

__device__ __forceinline__ float gelu_f(float x) {
  float u = 1.5957691216f * (x + 0.044715f * x * x * x);
  float t = exp2f(-1.4426950409f * u);
#if __has_builtin(__builtin_amdgcn_rcpf)
  return x * __builtin_amdgcn_rcpf(1.0f + t);
#else
  return x / (1.0f + t);
#endif
}

__device__ __forceinline__ float dot2f(f16x2 a, f16x2 b, float c) {
#if __has_builtin(__builtin_amdgcn_fdot2)
  return __builtin_amdgcn_fdot2(a, b, c, false);
#else
  return c + (float)a.x * (float)b.x + (float)a.y * (float)b.y;
#endif
}

// ---------------------------------------------------------------------------
__global__ void build_kappa_kernel(const float* __restrict__ fw1,
                                   const float* __restrict__ fw2,
                                   float* __restrict__ kap1,
                                   float* __restrict__ kap2) {
  int which = blockIdx.x >> 6, c = blockIdx.x & 63;
  const float* fw = which ? fw2 : fw1;
  float* kap = which ? kap2 : kap1;
  int t = threadIdx.x, a = t >> 3, bb = t & 7;
  __shared__ float Wt[64];
  __shared__ float ct[8];
  if (t == 0) {
    const float r2 = 0.70710678118654752440f;
    ct[0] = 1.f; ct[1] = r2; ct[2] = 0.f; ct[3] = -r2;
    ct[4] = -1.f; ct[5] = -r2; ct[6] = 0.f; ct[7] = r2;
  }
  {
    int u = a, v = bb;
    Wt[t] = (v <= 4) ? fw[c * 40 + u * 5 + v]
                     : fw[c * 40 + ((8 - u) & 7) * 5 + (8 - v)];
  }
  __syncthreads();
  float acc = 0.f;
  for (int u = 0; u < 8; ++u)
    for (int v = 0; v < 8; ++v)
      acc += Wt[u * 8 + v] * ct[(u * a + v * bb) & 7];
  kap[c * 64 + t] = acc * 0.015625f;
}

// ---------------------------------------------------------------------------
__global__ void preconv_kernel(const float* __restrict__ w0, const float* __restrict__ w1,
                               const float* __restrict__ w2, const float* __restrict__ w4,
                               const float* __restrict__ w3, const float* __restrict__ b3,
                               f16* __restrict__ W0h, f16* __restrict__ W1h,
                               f16* __restrict__ W2h, f16* __restrict__ W4h,
                               f16* __restrict__ w3pk, f16* __restrict__ b3pk) {
  int i = blockIdx.x * 256 + threadIdx.x;
  if (i < 16384) W0h[i] = (f16)w0[i];
  else if (i < 32768) W1h[i - 16384] = (f16)w1[i - 16384];
  else if (i < 49152) W2h[i - 32768] = (f16)w2[i - 32768];
  else if (i < 65536) W4h[i - 49152] = (f16)w4[i - 49152];
  else if (i < 67840) {
    int j = i - 65536;                 // [g][tap][k]: value = w3[(g*8+k)*9+tap]
    int g = j / 72, r = j % 72, tap = r >> 3, k = r & 7;
    w3pk[j] = (f16)w3[(g * 8 + k) * 9 + tap];
  } else if (i < 68096) {
    int k = i - 67840;
    b3pk[k] = (f16)b3[k];
  }
}

// ---------------------------------------------------------------------------
// LayerNorm.  x NCHW f32 -> xn NHWC f16.  grid (256, 4).
// ---------------------------------------------------------------------------
__global__ void __launch_bounds__(256) ln_kernel(const float* __restrict__ x,
                                                 const float* __restrict__ lnw,
                                                 const float* __restrict__ lnb,
                                                 f16* __restrict__ xn) {
  int b = blockIdx.y;
  int px = blockIdx.x * 256 + threadIdx.x;
  const float* xp = x + ((size_t)b << 22) + px;
  float v[64];
  float s = 0.f;
#pragma unroll
  for (int c = 0; c < 64; ++c) { v[c] = xp[(size_t)c << 16]; s += v[c]; }
  float mu = s * (1.f / 64.f), s2 = 0.f;
#pragma unroll
  for (int c = 0; c < 64; ++c) { float d = v[c] - mu; s2 += d * d; }
  float rstd = rsqrtf(s2 * (1.f / 64.f) + 1e-6f);
  f16* op = xn + (size_t)b * 4194304 + (size_t)px * 64;
#pragma unroll
  for (int g = 0; g < 8; ++g) {
    f16x8 pk;
#pragma unroll
    for (int j = 0; j < 8; ++j) {
      int c = g * 8 + j;
      pk[j] = (f16)((v[c] - mu) * rstd * lnw[c] + lnb[c]);
    }
    *(f16x8*)(op + g * 8) = pk;
  }
}

// ---------------------------------------------------------------------------
// 3x3 dense conv 16ci->16co on xn c<16 -> y1 NHWC f16.  grid (256, 4).
// ---------------------------------------------------------------------------
__global__ void __launch_bounds__(256) pconv_kernel(const f16* __restrict__ xn,
                                                    const float* __restrict__ pw,
                                                    const float* __restrict__ pb,
                                                    f16* __restrict__ y1) {
  __shared__ __align__(16) char halo[18 * 640];
  __shared__ f16 wpk[2304];                      // [co][tap][ci]
  __shared__ float pbs[16];
  int t = threadIdx.x, blk = blockIdx.x, b = blockIdx.y;
  const f16* xnb = xn + (size_t)b * 4194304;
  f16* y1b = y1 + (size_t)b * 1048576;
  int h0 = (blk >> 4) << 4, w0 = (blk & 15) << 4;
  for (int i = t; i < 2304; i += 256) {
    int co = i / 144, r = i % 144, tap = r >> 4, ci = r & 15;
    wpk[i] = (f16)pw[co * 144 + ci * 9 + tap];
  }
  if (t < 16) pbs[t] = pb[t];
  for (int i = 0; i < 3; ++i) {
    int u = i * 256 + t;
    if (u < 648) {
      int hp = u >> 1, half = u & 1;
      int hr = hp / 18, hc = hp - hr * 18;
      int h = h0 - 1 + hr, w = w0 - 1 + hc;
      f16x8 v = {0, 0, 0, 0, 0, 0, 0, 0};
      if ((unsigned)h < 256u && (unsigned)w < 256u)
        v = *(const f16x8*)(xnb + ((((size_t)h << 8)) + w) * 64 + half * 8);
      *(f16x8*)(halo + hr * 640 + ((hc * 32 + half * 16) ^ ((hr & 7) << 4))) = v;
    }
  }
  __syncthreads();
  int rl = t >> 4, cl = t & 15;
  float acc[16];
#pragma unroll
  for (int co = 0; co < 16; ++co) acc[co] = pbs[co];
#pragma unroll
  for (int ty = 0; ty < 3; ++ty)
#pragma unroll
    for (int tx = 0; tx < 3; ++tx) {
      int hr = rl + ty, hc = cl + tx, tap = ty * 3 + tx;
      f16x8 ld0 = *(const f16x8*)(halo + hr * 640 + ((hc * 32) ^ ((hr & 7) << 4)));
      f16x8 ld1 = *(const f16x8*)(halo + hr * 640 + ((hc * 32 + 16) ^ ((hr & 7) << 4)));
#pragma unroll
      for (int co = 0; co < 16; ++co) {
#pragma unroll
        for (int p = 0; p < 4; ++p) {
          f16x2 xp = {ld0[2 * p], ld0[2 * p + 1]};
          f16x2 wp = *(const f16x2*)&wpk[co * 144 + tap * 16 + 2 * p];
          acc[co] = dot2f(xp, wp, acc[co]);
        }
#pragma unroll
        for (int p = 0; p < 4; ++p) {
          f16x2 xp = {ld1[2 * p], ld1[2 * p + 1]};
          f16x2 wp = *(const f16x2*)&wpk[co * 144 + tap * 16 + 8 + 2 * p];
          acc[co] = dot2f(xp, wp, acc[co]);
        }
      }
    }
  size_t px = (((size_t)(h0 + rl)) << 8) + w0 + cl;
  f16x8 o0, o1;
#pragma unroll
  for (int j = 0; j < 8; ++j) { o0[j] = (f16)acc[j]; o1[j] = (f16)acc[8 + j]; }
  *(f16x8*)(y1b + px * 16) = o0;
  *(f16x8*)(y1b + px * 16 + 8) = o1;
}

// ---------------------------------------------------------------------------
// Fused branch 1: u1[co][px] = (gelu(xn.W0+b0)).W2 + b2, 128-px strips.
// grid (512, 4).  u1 plane: b<3 -> d_out overlay, b=3 -> ws.
// ---------------------------------------------------------------------------
__global__ void __launch_bounds__(256) b1_kernel(
    const f16* __restrict__ xn, const f16* __restrict__ W0h,
    const float* __restrict__ b0, const f16* __restrict__ W2h,
    const float* __restrict__ b2, f16* __restrict__ u1d,
    f16* __restrict__ u1w) {
  __shared__ __align__(16) f16 As[8192];   // xn strip [128 px][64 ci] swizzled
  __shared__ __align__(16) f16 Es[8192];   // e chunk [128 px][64 ce] swizzled
  int t = threadIdx.x, b = blockIdx.y;
  const f16* xnb = xn + (size_t)b * 4194304;
  f16* u1b = (b < 3) ? (u1d + (size_t)b * 4194304) : u1w;
  int px0 = blockIdx.x << 7;
#pragma unroll
  for (int i = 0; i < 4; ++i) {
    int u = i * 256 + t, row = u >> 3, cb = (u & 7) << 4;
    f16x8 v = *(const f16x8*)(xnb + (size_t)(px0 + row) * 64 + (cb >> 1));
    *(f16x8*)((char*)As + row * 128 + (cb ^ ((row & 7) << 4))) = v;
  }
  __syncthreads();
  int l = t & 63, wv = t >> 6, lm = l & 15, kg = l >> 4;
  f32x4 uacc[2][4];
#pragma unroll
  for (int a = 0; a < 2; ++a)
#pragma unroll
    for (int n = 0; n < 4; ++n) uacc[a][n] = (f32x4){0.f, 0.f, 0.f, 0.f};
  for (int cc = 0; cc < 4; ++cc) {
    f32x4 eacc[2][4];
#pragma unroll
    for (int a = 0; a < 2; ++a)
#pragma unroll
      for (int n = 0; n < 4; ++n) eacc[a][n] = (f32x4){0.f, 0.f, 0.f, 0.f};
#pragma unroll
    for (int kk = 0; kk < 2; ++kk) {
      int kb = kk * 64 + kg * 16;
      f16x8 af[2];
#pragma unroll
      for (int mt = 0; mt < 2; ++mt) {
        int row = wv * 32 + mt * 16 + lm;
        af[mt] = *(const f16x8*)((char*)As + row * 128 + (kb ^ ((row & 7) << 4)));
      }
      f16x8 bf[4];
#pragma unroll
      for (int nt = 0; nt < 4; ++nt) {
        int co = cc * 64 + nt * 16 + lm;
        bf[nt] = *(const f16x8*)(W0h + (size_t)co * 64 + kk * 32 + kg * 8);
      }
#pragma unroll
      for (int mt = 0; mt < 2; ++mt)
#pragma unroll
        for (int nt = 0; nt < 4; ++nt)
          eacc[mt][nt] = __builtin_amdgcn_mfma_f32_16x16x32_f16(af[mt], bf[nt], eacc[mt][nt], 0, 0, 0);
    }
    if (cc) __syncthreads();
#pragma unroll
    for (int mt = 0; mt < 2; ++mt)
#pragma unroll
      for (int nt = 0; nt < 4; ++nt) {
        int c = nt * 16 + lm;
        float bz = b0[cc * 64 + c];
#pragma unroll
        for (int r = 0; r < 4; ++r) {
          int m = wv * 32 + mt * 16 + kg * 4 + r;
          *(f16*)((char*)Es + m * 128 + ((c * 2) ^ ((m & 7) << 4))) =
              (f16)gelu_f(eacc[mt][nt][r] + bz);
        }
      }
    __syncthreads();
#pragma unroll
    for (int kk = 0; kk < 2; ++kk) {
      int kb = kk * 64 + kg * 16;
      f16x8 af[2];
#pragma unroll
      for (int mt = 0; mt < 2; ++mt) {
        int row = wv * 32 + mt * 16 + lm;
        af[mt] = *(const f16x8*)((char*)Es + row * 128 + (kb ^ ((row & 7) << 4)));
      }
      f16x8 bf[4];
#pragma unroll
      for (int nt = 0; nt < 4; ++nt) {
        int co = nt * 16 + lm;
        bf[nt] = *(const f16x8*)(W2h + (size_t)co * 256 + cc * 64 + kk * 32 + kg * 8);
      }
#pragma unroll
      for (int mt = 0; mt < 2; ++mt)
#pragma unroll
        for (int nt = 0; nt < 4; ++nt)
          uacc[mt][nt] = __builtin_amdgcn_mfma_f32_16x16x32_f16(af[mt], bf[nt], uacc[mt][nt], 0, 0, 0);
    }
    __syncthreads();
  }
#pragma unroll
  for (int mt = 0; mt < 2; ++mt)
#pragma unroll
    for (int nt = 0; nt < 4; ++nt) {
      int c = nt * 16 + lm;
      float bz = b2[c];
#pragma unroll
      for (int r = 0; r < 4; ++r) {
        int m = wv * 32 + mt * 16 + kg * 4 + r;
        *(f16*)((char*)Es + m * 128 + ((c * 2) ^ ((m & 7) << 4))) =
            (f16)(uacc[mt][nt][r] + bz);
      }
    }
  __syncthreads();
  int co = t >> 2, q = t & 3;
  f16x8 o[4];
#pragma unroll
  for (int i = 0; i < 32; ++i) {
    int m = q * 32 + i;
    o[i >> 3][i & 7] =
        *(const f16*)((char*)Es + m * 128 + ((co * 2) ^ ((m & 7) << 4)));
  }
  f16* up = u1b + ((size_t)co << 16) + px0 + q * 32;
#pragma unroll
  for (int ss = 0; ss < 4; ++ss) *(f16x8*)(up + ss * 8) = o[ss];
}

// ---------------------------------------------------------------------------
// Fused branch 2: expand1(halo recompute) + dw3x3 + gelu + contract2 -> u2.
// 8x16 output tile, 10x18 halo (192 padded rows).  Per kc(4) x sub(2):
// expand 32 ce -> Es(LDS) -> dw+gelu -> Gs(LDS) -> contract K=32 partial.
// Es/Gs rows are 64 B (16 banks); swizzle uses ((row>>1)&3)<<4 so that
// combined with the natural 16*(row&1) bank base, rows cover all 8
// 16B-slots (round-7 bug: (row&3)<<4 covered only 4 -> 20.4M conflicts).
// grid (512, 4).
// ---------------------------------------------------------------------------
__global__ void __launch_bounds__(256) b2_kernel(
    const f16* __restrict__ xn, const f16* __restrict__ y1,
    const f16* __restrict__ W1h, const float* __restrict__ b1v,
    const f16* __restrict__ W4h, const float* __restrict__ b4,
    const f16* __restrict__ w3pk, const f16* __restrict__ b3pk,
    f16* __restrict__ u2) {
  __shared__ __align__(16) f16 xin[12288];  // 192 rows x 64 ci, 128B rows, &7 swz
  __shared__ __align__(16) f16 Es[6144];    // 192 rows x 32 ce, 64B rows
  __shared__ __align__(16) f16 Gs[4096];    // 128 px x 32 ce, 64B rows
  __shared__ __align__(16) f16 w3s[2304];
  __shared__ __align__(16) f16 b3s[256];
  int t = threadIdx.x, blk = blockIdx.x, b = blockIdx.y;
  const f16* xnb = xn + (size_t)b * 4194304;
  const f16* y1b = y1 + (size_t)b * 1048576;
  f16* u2b = u2 + (size_t)b * 4194304;
  int h0 = (blk >> 4) << 3, w0 = (blk & 15) << 4;
  for (int i = t; i < 288; i += 256)
    *(f16x8*)(w3s + i * 8) = *(const f16x8*)(w3pk + i * 8);
  if (t < 32) *(f16x8*)(b3s + t * 8) = *(const f16x8*)(b3pk + t * 8);
  // stage xin: halo rows hp = hr*18+hc (hr 0..9, hc 0..17); rows 180..191 zero
#pragma unroll
  for (int i = 0; i < 6; ++i) {
    int u = i * 256 + t;                 // 0..1535 = 192 rows x 8 parts
    int hp = u >> 3, part = u & 7;
    f16x8 v = {0, 0, 0, 0, 0, 0, 0, 0};
    if (hp < 180) {
      int hr = hp / 18, hc = hp - hr * 18;
      int h = h0 - 1 + hr, w = w0 - 1 + hc;
      if ((unsigned)h < 256u && (unsigned)w < 256u) {
        size_t px = ((size_t)h << 8) + w;
        v = (part < 2) ? *(const f16x8*)(y1b + px * 16 + part * 8)
                       : *(const f16x8*)(xnb + px * 64 + part * 8);
      }
    }
    *(f16x8*)((char*)xin + hp * 128 + ((part * 16) ^ ((hp & 7) << 4))) = v;
  }
  __syncthreads();
  int l = t & 63, wv = t >> 6, lm = l & 15, kg = l >> 4;
  int pxl = t & 127, chh = t >> 7, rl = pxl >> 4, cl = pxl & 15;
  f32x4 uacc[2][4];
#pragma unroll
  for (int a = 0; a < 2; ++a)
#pragma unroll
    for (int n = 0; n < 4; ++n) uacc[a][n] = (f32x4){0.f, 0.f, 0.f, 0.f};
  for (int kc = 0; kc < 4; ++kc) {
#pragma unroll
    for (int sub = 0; sub < 2; ++sub) {
      int ce0 = kc * 64 + sub * 32;
      // --- expand: Es[192 rows][32 ce] (12 m-tiles: wave wv does wv,wv+4,wv+8)
      f32x4 eacc[3][2];
#pragma unroll
      for (int a = 0; a < 3; ++a)
#pragma unroll
        for (int n = 0; n < 2; ++n) eacc[a][n] = (f32x4){0.f, 0.f, 0.f, 0.f};
#pragma unroll
      for (int kk = 0; kk < 2; ++kk) {
        int kb = kk * 64 + kg * 16;
        f16x8 af[3];
#pragma unroll
        for (int mtl = 0; mtl < 3; ++mtl) {
          int row = (mtl * 4 + wv) * 16 + lm;
          af[mtl] = *(const f16x8*)((char*)xin + row * 128 + (kb ^ ((row & 7) << 4)));
        }
        f16x8 bf[2];
#pragma unroll
        for (int nt = 0; nt < 2; ++nt) {
          int ce = ce0 + nt * 16 + lm;
          bf[nt] = *(const f16x8*)(W1h + (size_t)ce * 64 + kk * 32 + kg * 8);
        }
#pragma unroll
        for (int mtl = 0; mtl < 3; ++mtl)
#pragma unroll
          for (int nt = 0; nt < 2; ++nt)
            eacc[mtl][nt] = __builtin_amdgcn_mfma_f32_16x16x32_f16(af[mtl], bf[nt], eacc[mtl][nt], 0, 0, 0);
      }
      float bz0 = b1v[ce0 + lm], bz1 = b1v[ce0 + 16 + lm];
#pragma unroll
      for (int mtl = 0; mtl < 3; ++mtl)
#pragma unroll
        for (int nt = 0; nt < 2; ++nt) {
          int ceL = nt * 16 + lm;
          float bz = nt ? bz1 : bz0;
#pragma unroll
          for (int r = 0; r < 4; ++r) {
            int row = (mtl * 4 + wv) * 16 + kg * 4 + r;
            *(f16*)((char*)Es + row * 64 + ((ceL * 2) ^ (((row >> 1) & 3) << 4))) =
                (f16)gelu_f(eacc[mtl][nt][r] + bz);
          }
        }
      __syncthreads();
      // --- dw 3x3 + gelu -> Gs[128 px][32 ce]
#pragma unroll
      for (int c8 = 0; c8 < 2; ++c8) {
        int ceL = chh * 16 + c8 * 8;
        int ceG = ce0 + ceL, g9 = ceG >> 3;
        f16x8 a8 = *(const f16x8*)(b3s + ceG);
#pragma unroll
        for (int ty = 0; ty < 3; ++ty)
#pragma unroll
          for (int tx = 0; tx < 3; ++tx) {
            int hp = (rl + ty) * 18 + (cl + tx);
            f16x8 xv = *(const f16x8*)((char*)Es + hp * 64 + ((ceL * 2) ^ (((hp >> 1) & 3) << 4)));
            f16x8 wv8 = *(const f16x8*)(w3s + g9 * 72 + (ty * 3 + tx) * 8);
            a8 += xv * wv8;
          }
        f16x8 r8;
#pragma unroll
        for (int j2 = 0; j2 < 8; ++j2) r8[j2] = (f16)gelu_f((float)a8[j2]);
        *(f16x8*)((char*)Gs + pxl * 64 + ((ceL * 2) ^ (((pxl >> 1) & 3) << 4))) = r8;
      }
      __syncthreads();
      // --- contract partial (K=32)
      f16x8 af2[2];
#pragma unroll
      for (int mt = 0; mt < 2; ++mt) {
        int row = wv * 32 + mt * 16 + lm;
        af2[mt] = *(const f16x8*)((char*)Gs + row * 64 + ((kg * 16) ^ (((row >> 1) & 3) << 4)));
      }
      f16x8 bf2[4];
#pragma unroll
      for (int nt = 0; nt < 4; ++nt) {
        int co = nt * 16 + lm;
        bf2[nt] = *(const f16x8*)(W4h + (size_t)co * 256 + ce0 + kg * 8);
      }
#pragma unroll
      for (int mt = 0; mt < 2; ++mt)
#pragma unroll
        for (int nt = 0; nt < 4; ++nt)
          uacc[mt][nt] = __builtin_amdgcn_mfma_f32_16x16x32_f16(af2[mt], bf2[nt], uacc[mt][nt], 0, 0, 0);
      __syncthreads();
    }
  }
  // --- epilogue: uacc + b4 -> xin (dead) -> coalesced u2 write
#pragma unroll
  for (int mt = 0; mt < 2; ++mt)
#pragma unroll
    for (int nt = 0; nt < 4; ++nt) {
      int c = nt * 16 + lm;
      float bz = b4[c];
#pragma unroll
      for (int r = 0; r < 4; ++r) {
        int m = wv * 32 + mt * 16 + kg * 4 + r;
        *(f16*)((char*)xin + m * 128 + ((c * 2) ^ ((m & 7) << 4))) =
            (f16)(uacc[mt][nt][r] + bz);
      }
    }
  __syncthreads();
  int co = t >> 2, q = t & 3;
  f16x8 o[4];
#pragma unroll
  for (int i = 0; i < 32; ++i) {
    int m = q * 32 + i;
    o[i >> 3][i & 7] =
        *(const f16*)((char*)xin + m * 128 + ((co * 2) ^ ((m & 7) << 4)));
  }
  f16* up = u2b + ((size_t)co << 16) + (size_t)(h0 + 2 * q) * 256 + w0;
  *(f16x8*)(up) = o[0];
  *(f16x8*)(up + 8) = o[1];
  *(f16x8*)(up + 256) = o[2];
  *(f16x8*)(up + 256 + 8) = o[3];
}

// ---------------------------------------------------------------------------
// out(b) = circconv8x8(u1,k1) + circconv8x8(u2,k2).  Per batch, grid 512.
// ---------------------------------------------------------------------------
__global__ void __launch_bounds__(256) fftmix_kernel(
    const f16* __restrict__ u1, const f16* __restrict__ u2,
    const float* __restrict__ kap1, const float* __restrict__ kap2,
    float* __restrict__ out, int b) {
  int blk = blockIdx.x;
  int c = blk >> 3, part = blk & 7;
  int t = threadIdx.x;
  int l = t & 63, wv = (t >> 6) & 3;
  int s = l >> 3, tq = l & 7;
  __shared__ unsigned int kls[64];
  if (t < 64) {
    f16 k1 = (f16)kap1[(c << 6) + t];
    f16 k2 = (f16)kap2[(c << 6) + t];
    kls[t] = (unsigned int)__builtin_bit_cast(unsigned short, k1) |
             ((unsigned int)__builtin_bit_cast(unsigned short, k2) << 16);
  }
  __syncthreads();
  unsigned int kp[64];
#pragma unroll
  for (int j = 0; j < 64; ++j) {
    int idx = (((s - (j >> 3)) & 7) << 3) | ((tq - (j & 7)) & 7);
    kp[j] = kls[idx];
  }
  size_t cb = ((size_t)c) << 16;
  size_t obase = ((size_t)(b * 64 + c)) << 16;
  int win0 = part * 128 + wv * 32;
  for (int it = 0; it < 32; ++it) {
    int win = win0 + it;
    int wh = win >> 5, ww = win & 31;
    size_t pix = (size_t)((wh * 8 + s) << 8) + ww * 8 + tq;
    unsigned int pk =
        (unsigned int)__builtin_bit_cast(unsigned short, u1[cb + pix]) |
        ((unsigned int)__builtin_bit_cast(unsigned short, u2[cb + pix]) << 16);
    float acc = 0.f;
#pragma unroll
    for (int j = 0; j < 64; ++j) {
      unsigned int bc = (unsigned int)__builtin_amdgcn_readlane((int)pk, j);
      acc = dot2f(__builtin_bit_cast(f16x2, bc),
                  __builtin_bit_cast(f16x2, kp[j]), acc);
    }
    out[obase + pix] = acc;
  }
}

// ---------------------------------------------------------------------------
__global__ void diag_kernel(float* __restrict__ out, float code, int n) {
  int i = blockIdx.x * 256 + threadIdx.x;
  for (int p = i; p < n; p += 256 * 4096) out[p] = (p == 0) ? code : 0.f;
}

// ---------------------------------------------------------------------------
extern "C" void kernel_launch(void* const* d_in, const int* in_sizes, int n_in,
                              void* d_out, int out_size, void* d_ws,
                              size_t ws_size, hipStream_t stream) {
  const float* x       = (const float*)d_in[0];
  const float* ln_w    = (const float*)d_in[1];
  const float* ln_b    = (const float*)d_in[2];
  const float* pconv_w = (const float*)d_in[3];
  const float* pconv_b = (const float*)d_in[4];
  const float* w0      = (const float*)d_in[5];
  const float* b0      = (const float*)d_in[6];
  const float* w1      = (const float*)d_in[7];
  const float* b1      = (const float*)d_in[8];
  const float* w2      = (const float*)d_in[9];
  const float* b2      = (const float*)d_in[10];
  const float* w3      = (const float*)d_in[11];
  const float* b3      = (const float*)d_in[12];
  const float* w4      = (const float*)d_in[13];
  const float* b4      = (const float*)d_in[14];
  const float* fftw1   = (const float*)d_in[15];
  const float* fftw2   = (const float*)d_in[16];

  const size_t OFF_KAP1 = 0;                        // f32 [64][64] = 16 KB
  const size_t OFF_KAP2 = 16384;
  const size_t OFF_W0H  = 32768;                    // 32 KB each
  const size_t OFF_W1H  = 65536;
  const size_t OFF_W2H  = 98304;
  const size_t OFF_W4H  = 131072;
  const size_t OFF_W3PK = 163840;                   // 4608 B
  const size_t OFF_B3PK = 168448;                   // 512 B
  const size_t OFF_Y1   = 168960;                   // f16 4 x [65536][16] = 8 MB
  const size_t OFF_U2   = OFF_Y1 + 8388608ull;      // f16 4 x [64][65536] = 32 MB
  const size_t OFF_U13  = OFF_U2 + 33554432ull;     // f16 [64][65536] = 8 MB (b=3)
  const size_t WS_NEED  = OFF_U13 + 8388608ull;     // 50,500,608 B (proven fits)

  float* outF = (float*)d_out;
  if (ws_size < WS_NEED) {
    diag_kernel<<<4096, 256, 0, stream>>>(outF, 1000.0f + (float)(ws_size >> 20), 16777216);
    return;
  }
  char* ws = (char*)d_ws;
  float* kap1 = (float*)(ws + OFF_KAP1);
  float* kap2 = (float*)(ws + OFF_KAP2);
  f16* W0h  = (f16*)(ws + OFF_W0H);
  f16* W1h  = (f16*)(ws + OFF_W1H);
  f16* W2h  = (f16*)(ws + OFF_W2H);
  f16* W4h  = (f16*)(ws + OFF_W4H);
  f16* w3pk = (f16*)(ws + OFF_W3PK);
  f16* b3pk = (f16*)(ws + OFF_B3PK);
  f16* Y1   = (f16*)(ws + OFF_Y1);
  f16* U2   = (f16*)(ws + OFF_U2);
  f16* U13  = (f16*)(ws + OFF_U13);

  // d_out overlay: xn = f16[0:32MB); u1(b<3) = f16[32MB + 8MB*b)
  f16* XN  = (f16*)d_out;
  f16* U1D = (f16*)d_out + 16777216;

  build_kappa_kernel<<<128, 64, 0, stream>>>(fftw1, fftw2, kap1, kap2);
  preconv_kernel<<<266, 256, 0, stream>>>(w0, w1, w2, w4, w3, b3,
                                          W0h, W1h, W2h, W4h, w3pk, b3pk);
  ln_kernel<<<dim3(256, 4), 256, 0, stream>>>(x, ln_w, ln_b, XN);
  pconv_kernel<<<dim3(256, 4), 256, 0, stream>>>(XN, pconv_w, pconv_b, Y1);
  b1_kernel<<<dim3(512, 4), 256, 0, stream>>>(XN, W0h, b0, W2h, b2, U1D, U13);
  b2_kernel<<<dim3(512, 4), 256, 0, stream>>>(XN, Y1, W1h, b1, W4h, b4,
                                              w3pk, b3pk, U2);
  for (int b = 0; b < 4; ++b) {
    const f16* u1b = (b < 3) ? (U1D + (size_t)b * 4194304) : U13;
    fftmix_kernel<<<512, 256, 0, stream>>>(u1b, U2 + (size_t)b * 4194304,
                                           kap1, kap2, outF, b);
  }
}